// Round 2
// baseline (8993.104 us; speedup 1.0000x reference)
//
#include <hip/hip_runtime.h>
#include <math.h>

constexpr int NANCH = 3136;           // 28*28*4
constexpr float SCORE_T = 0.7f;
constexpr float IOU_T = 0.3f;
constexpr int MAXP = 10;

// =====================================================================
// Generic 3x3 conv, pad=1, NCHW. Each block: 32x32 conv-output tile for
// OCB out-channels; 256 threads, each owns a 2x2 pixel quad.
// MODE 0: + bias (+BN) + ReLU, write HxW
// MODE 1: + bias (+BN) + ReLU + 2x2 maxpool, write H/2 x W/2
// MODE 2: + bias + BN + ReLU + mean over the 32x32 tile -> out[b][oc][by][bx]
// =====================================================================
template<int CIN, int CK, int OCB, bool BN, int MODE>
__global__ __launch_bounds__(256) void conv_k(
    const float* __restrict__ in, const float* __restrict__ wgt,
    const float* __restrict__ bias, const float* __restrict__ gamma,
    const float* __restrict__ beta, float* __restrict__ out,
    int H, int W, int COUT) {
  const int tid = threadIdx.x;
  const int tx = tid & 15, ty = tid >> 4;
  const int ng = COUT / OCB;
  const int b  = blockIdx.z / ng;
  const int oc0 = (blockIdx.z % ng) * OCB;
  __shared__ float s_in[CK][34][34];
  __shared__ float s_w[CK][3][3][OCB];
  __shared__ float s_red[256];

  float acc[OCB][2][2];
#pragma unroll
  for (int o = 0; o < OCB; o++) {
    acc[o][0][0] = 0.f; acc[o][0][1] = 0.f; acc[o][1][0] = 0.f; acc[o][1][1] = 0.f;
  }
  const int y0 = blockIdx.y * 32 - 1, x0 = blockIdx.x * 32 - 1;

  for (int ck0 = 0; ck0 < CIN; ck0 += CK) {
    // stage input patch 34x34xCK (zero-padded at image borders)
    for (int t = tid; t < CK * 34 * 34; t += 256) {
      const int ck = t / 1156; const int r = t % 1156;
      const int iy = r / 34, ix = r % 34;
      const int gy = y0 + iy, gx = x0 + ix;
      float v = 0.f;
      if ((unsigned)gy < (unsigned)H && (unsigned)gx < (unsigned)W)
        v = in[(((size_t)b * CIN + ck0 + ck) * H + gy) * W + gx];
      s_in[ck][iy][ix] = v;
    }
    // stage weights [ck][ky][kx][oc]
    for (int t = tid; t < CK * 9 * OCB; t += 256) {
      const int oc = t % OCB; int r = t / OCB;
      const int kx = r % 3; r /= 3; const int ky = r % 3; const int ck = r / 3;
      s_w[ck][ky][kx][oc] = wgt[(((size_t)(oc0 + oc) * CIN + (ck0 + ck)) * 3 + ky) * 3 + kx];
    }
    __syncthreads();

#pragma unroll 2
    for (int ck = 0; ck < CK; ck++) {
#pragma unroll
      for (int ky = 0; ky < 3; ky++) {
#pragma unroll
        for (int kx = 0; kx < 3; kx++) {
          float w8[OCB];
#pragma unroll
          for (int o = 0; o < OCB; o++) w8[o] = s_w[ck][ky][kx][o];   // contiguous -> b128 merge, broadcast
          float xv[2][2];
#pragma unroll
          for (int dy = 0; dy < 2; dy++)
#pragma unroll
            for (int dx = 0; dx < 2; dx++)
              xv[dy][dx] = s_in[ck][2 * ty + dy + ky][2 * tx + dx + kx]; // stride-2: free 2-way
#pragma unroll
          for (int o = 0; o < OCB; o++)
#pragma unroll
            for (int dy = 0; dy < 2; dy++)
#pragma unroll
              for (int dx = 0; dx < 2; dx++)
                acc[o][dy][dx] = fmaf(w8[o], xv[dy][dx], acc[o][dy][dx]);
        }
      }
    }
    __syncthreads();
  }

  // epilogue
#pragma unroll
  for (int o = 0; o < OCB; o++) {
    const int oc = oc0 + o;
    const float bi = bias[oc];
    float scl = 1.f, shf = 0.f;
    if (BN) { scl = gamma[oc] * (1.f / sqrtf(1.f + 1e-5f)); shf = beta[oc]; }

    if (MODE == 0) {
#pragma unroll
      for (int dy = 0; dy < 2; dy++)
#pragma unroll
        for (int dx = 0; dx < 2; dx++) {
          const int oy = blockIdx.y * 32 + 2 * ty + dy;
          const int ox = blockIdx.x * 32 + 2 * tx + dx;
          if (oy < H && ox < W) {
            const float e = (acc[o][dy][dx] + bi) * scl + shf;
            out[(((size_t)b * COUT + oc) * H + oy) * W + ox] = fmaxf(e, 0.f);
          }
        }
    } else if (MODE == 1) {
      const int PH = H >> 1, PW = W >> 1;
      const int py = blockIdx.y * 16 + ty, px = blockIdx.x * 16 + tx;
      if (py < PH && px < PW) {
        // affine per element (scale may be negative), then max, then ReLU
        float m = (acc[o][0][0] + bi) * scl + shf;
        m = fmaxf(m, (acc[o][0][1] + bi) * scl + shf);
        m = fmaxf(m, (acc[o][1][0] + bi) * scl + shf);
        m = fmaxf(m, (acc[o][1][1] + bi) * scl + shf);
        out[(((size_t)b * COUT + oc) * PH + py) * PW + px] = fmaxf(m, 0.f);
      }
    } else { // MODE 2: mean of ReLU over the 32x32 tile
      float s = 0.f;
#pragma unroll
      for (int dy = 0; dy < 2; dy++)
#pragma unroll
        for (int dx = 0; dx < 2; dx++)
          s += fmaxf((acc[o][dy][dx] + bi) * scl + shf, 0.f);
      s_red[tid] = s; __syncthreads();
      for (int st = 128; st > 0; st >>= 1) {
        if (tid < st) s_red[tid] += s_red[tid + st];
        __syncthreads();
      }
      if (tid == 0)
        out[(((size_t)b * COUT + oc) * 7 + blockIdx.y) * 7 + blockIdx.x] = s_red[0] * (1.f / 1024.f);
      __syncthreads();
    }
  }
}

// =====================================================================
// RPN head: 1x1 cls/reg convs + softmax prob + anchor decode.
// One thread per (b,y,x,a). gid = b*3136 + (y*28+x)*4 + a.
// =====================================================================
__global__ __launch_bounds__(256) void rpn_head_k(
    const float* __restrict__ feat,      // [B,256,28,28]
    const float* __restrict__ clsw, const float* __restrict__ clsb,
    const float* __restrict__ regw, const float* __restrict__ regb,
    float* __restrict__ probs, float* __restrict__ boxes) {
  const int gid = blockIdx.x * 256 + threadIdx.x;
  if (gid >= 32 * NANCH) return;
  const int a = gid & 3;
  int r = gid >> 2;
  const int x = r % 28; r /= 28;
  const int y = r % 28;
  const int b = r / 28;

  const float* f = feat + (size_t)b * 256 * 784 + y * 28 + x;
  float c0 = clsb[2 * a], c1 = clsb[2 * a + 1];
  float r0 = regb[4 * a], r1 = regb[4 * a + 1], r2 = regb[4 * a + 2], r3 = regb[4 * a + 3];
#pragma unroll 4
  for (int c = 0; c < 256; c++) {
    const float fv = f[(size_t)c * 784];
    c0 = fmaf(fv, clsw[(2 * a) * 256 + c], c0);
    c1 = fmaf(fv, clsw[(2 * a + 1) * 256 + c], c1);
    r0 = fmaf(fv, regw[(4 * a) * 256 + c], r0);
    r1 = fmaf(fv, regw[(4 * a + 1) * 256 + c], r1);
    r2 = fmaf(fv, regw[(4 * a + 2) * 256 + c], r2);
    r3 = fmaf(fv, regw[(4 * a + 3) * 256 + c], r3);
  }
  const float p = 1.f / (1.f + expf(c0 - c1));   // softmax(...)[1]

  const float cx = (x + 0.5f) * (1.f / 28.f);
  const float cy = (y + 0.5f) * (1.f / 28.f);
  const float sz = (float)(16 << a) * (1.f / 224.f);
  const float ncx = cx + r0 * 0.1f, ncy = cy + r1 * 0.1f;
  const float nw = sz * expf(r2 * 0.2f), nh = sz * expf(r3 * 0.2f);
  const float x1 = fminf(fmaxf(ncx - nw * 0.5f, 0.f), 1.f);
  const float y1 = fminf(fmaxf(ncy - nh * 0.5f, 0.f), 1.f);
  const float x2 = fminf(fmaxf(ncx + nw * 0.5f, 0.f), 1.f);
  const float y2 = fminf(fmaxf(ncy + nh * 0.5f, 0.f), 1.f);

  probs[gid] = p;
  ((float4*)boxes)[gid] = make_float4(x1, y1, x2, y2);
}

// =====================================================================
// Greedy NMS, one block per image. Matches jax.lax.scan reference:
// argmax (first-index tie-break), ok = s[i] > -inf, suppress iou>T | ==i.
// Writes kept_boxes / kept_scores / oks into d_out, has_prop flag to ws.
// =====================================================================
__global__ __launch_bounds__(256) void nms_k(
    const float* __restrict__ probs, const float* __restrict__ boxes,
    float* __restrict__ dout, int* __restrict__ hasflag) {
  const int b = blockIdx.x;
  const int t = threadIdx.x;
  __shared__ float sc[NANCH];
  __shared__ float ar[NANCH];
  __shared__ float4 bx[NANCH];
  __shared__ float rv[256];
  __shared__ int   ri[256];
  __shared__ int s_any, s_sel[MAXP], s_ok[MAXP];

  if (t == 0) s_any = 0;
  __syncthreads();

  int anyl = 0;
  for (int i = t; i < NANCH; i += 256) {
    const float p = probs[(size_t)b * NANCH + i];
    const float4 bb = ((const float4*)boxes)[(size_t)b * NANCH + i];
    bx[i] = bb;
    ar[i] = (bb.z - bb.x) * (bb.w - bb.y);
    sc[i] = (p > SCORE_T) ? p : -INFINITY;
    if (p > SCORE_T) anyl = 1;
  }
  if (anyl) atomicOr(&s_any, 1);
  __syncthreads();

  for (int it = 0; it < MAXP; ++it) {
    // ---- argmax with first-index tie-break (all -inf -> 0) ----
    float bv = -INFINITY; int bi = 0x7fffffff;
    for (int i = t; i < NANCH; i += 256) {
      const float v = sc[i];
      if (v > bv || (v == bv && i < bi)) { bv = v; bi = i; }
    }
    rv[t] = bv; ri[t] = bi;
    __syncthreads();
    for (int st = 128; st > 0; st >>= 1) {
      if (t < st) {
        const float ov = rv[t + st]; const int oi = ri[t + st];
        if (ov > rv[t] || (ov == rv[t] && oi < ri[t])) { rv[t] = ov; ri[t] = oi; }
      }
      __syncthreads();
    }
    if (t == 0) { s_sel[it] = ri[0]; s_ok[it] = (rv[0] > -INFINITY) ? 1 : 0; }
    __syncthreads();
    const int sel = s_sel[it];
    const int ok  = s_ok[it];
    if (ok) {
      const float4 bs = bx[sel]; const float as = ar[sel];
      for (int i = t; i < NANCH; i += 256) {
        const float xx1 = fmaxf(bs.x, bx[i].x), yy1 = fmaxf(bs.y, bx[i].y);
        const float xx2 = fminf(bs.z, bx[i].z), yy2 = fminf(bs.w, bx[i].w);
        const float inter = fmaxf(xx2 - xx1, 0.f) * fmaxf(yy2 - yy1, 0.f);
        const float iou = inter / (as + ar[i] - inter);   // NaN -> not suppressed (matches JAX)
        if (iou > IOU_T || i == sel) sc[i] = -INFINITY;
      }
    }
    __syncthreads();
  }

  if (t < MAXP) {
    const int sel = s_ok[t] ? s_sel[t] : 0;
    const float okf = s_ok[t] ? 1.f : 0.f;
    const float4 bb = bx[sel];
    float* kb = dout + 64;                       // kept_boxes [32,10,4]
    float* ks = dout + 64 + 32 * MAXP * 4;       // kept_scores [32,10]
    float* ko = dout + 64 + 32 * MAXP * 5;       // oks [32,10]
    const size_t base = ((size_t)b * MAXP + t) * 4;
    kb[base + 0] = bb.x * okf; kb[base + 1] = bb.y * okf;
    kb[base + 2] = bb.z * okf; kb[base + 3] = bb.w * okf;
    ks[b * MAXP + t] = probs[(size_t)b * NANCH + sel] * okf;
    ko[b * MAXP + t] = okf;
  }
  if (t == 0) hasflag[b] = s_any;
}

// =====================================================================
// FC layer: one block per batch row; x row staged in LDS; coalesced W.
// =====================================================================
__global__ __launch_bounds__(256) void fc_k(
    const float* __restrict__ x, const float* __restrict__ w,
    const float* __restrict__ bi, float* __restrict__ y,
    int K, int N, int dorelu) {
  __shared__ float sx[6272];
  const int b = blockIdx.x;
  for (int i = threadIdx.x; i < K; i += 256) sx[i] = x[(size_t)b * K + i];
  __syncthreads();
  for (int o = threadIdx.x; o < N; o += 256) {
    float acc = bi[o];
    for (int k = 0; k < K; k++) acc = fmaf(sx[k], w[(size_t)k * N + o], acc);
    if (dorelu) acc = fmaxf(acc, 0.f);
    y[(size_t)b * N + o] = acc;
  }
}

__global__ __launch_bounds__(64) void final_k(
    const float* __restrict__ f3, const float* __restrict__ w,
    const float* __restrict__ bi, const int* __restrict__ hasflag,
    float* __restrict__ dout) {
  const int t = threadIdx.x;
  if (t >= 64) return;
  const int b = t >> 1, j = t & 1;
  float acc = bi[j];
#pragma unroll 4
  for (int k = 0; k < 128; k++) acc = fmaf(f3[b * 128 + k], w[k * 2 + j], acc);
  dout[b * 2 + j] = hasflag[b] ? acc : (j == 0 ? 1.f : 0.f);
}

// =====================================================================
extern "C" void kernel_launch(void* const* d_in, const int* in_sizes, int n_in,
                              void* d_out, int out_size, void* d_ws, size_t ws_size,
                              hipStream_t stream) {
  const float* x    = (const float*)d_in[0];
  const float* r1w  = (const float*)d_in[1];  const float* r1b = (const float*)d_in[2];
  const float* g1   = (const float*)d_in[3];  const float* b1  = (const float*)d_in[4];
  const float* r2w  = (const float*)d_in[5];  const float* r2b = (const float*)d_in[6];
  const float* g2   = (const float*)d_in[7];  const float* b2  = (const float*)d_in[8];
  const float* r3w  = (const float*)d_in[9];  const float* r3b = (const float*)d_in[10];
  const float* g3   = (const float*)d_in[11]; const float* b3  = (const float*)d_in[12];
  const float* rpw  = (const float*)d_in[13]; const float* rpb = (const float*)d_in[14];
  const float* clsw = (const float*)d_in[15]; const float* clsb = (const float*)d_in[16];
  const float* regw = (const float*)d_in[17]; const float* regb = (const float*)d_in[18];
  const float* c1w  = (const float*)d_in[19]; const float* c1b = (const float*)d_in[20];
  const float* cg1  = (const float*)d_in[21]; const float* cb1 = (const float*)d_in[22];
  const float* c2w  = (const float*)d_in[23]; const float* c2b = (const float*)d_in[24];
  const float* cg2  = (const float*)d_in[25]; const float* cb2 = (const float*)d_in[26];
  const float* fc1w = (const float*)d_in[27]; const float* fc1b = (const float*)d_in[28];
  const float* fc2w = (const float*)d_in[29]; const float* fc2b = (const float*)d_in[30];
  const float* fc3w = (const float*)d_in[31]; const float* fc3b = (const float*)d_in[32];
  const float* fc4w = (const float*)d_in[33]; const float* fc4b = (const float*)d_in[34];
  float* dout = (float*)d_out;
  float* Wp = (float*)d_ws;

  // workspace layout (floats). c1buf ALIASES h1 (dead once h2 exists; stage-2
  // runs after NMS in stream order). chunk=4: 4*64*224*224 == |h1| exactly.
  const size_t o_h1   = 0;                               // [32,32,112,112] = 12,845,056
  const size_t o_h2   = o_h1 + (size_t)32*32*112*112;    // [32,64,56,56]
  const size_t o_h3   = o_h2 + (size_t)32*64*56*56;      // [32,128,28,28]
  const size_t o_h4   = o_h3 + (size_t)32*128*28*28;     // [32,256,28,28]
  const size_t o_prob = o_h4 + (size_t)32*256*28*28;     // [32,3136]
  const size_t o_box  = o_prob + (size_t)32*3136;        // [32,3136,4]
  const size_t o_flag = o_box + (size_t)32*3136*4;       // [32] int
  const size_t o_pool = o_flag + 32;                     // [32,6272]
  const size_t o_f1   = o_pool + (size_t)32*6272;        // [32,512]
  const size_t o_f2   = o_f1 + 32*512;                   // [32,256]
  const size_t o_f3   = o_f2 + 32*256;                   // [32,128]

  float* h1 = Wp + o_h1; float* h2 = Wp + o_h2; float* h3 = Wp + o_h3; float* h4 = Wp + o_h4;
  float* probs = Wp + o_prob; float* boxes = Wp + o_box;
  int* hasflag = (int*)(Wp + o_flag);
  float* pooled = Wp + o_pool;
  float* f1 = Wp + o_f1; float* f2 = Wp + o_f2; float* f3 = Wp + o_f3;
  float* c1buf = h1;   // alias: stage-2 activation reuses h1's 12.8M floats

  // ---- Stage 1: RPN backbone ----
  conv_k<4, 4, 8, true, 1><<<dim3(7, 7, 32 * 4), 256, 0, stream>>>(x,  r1w, r1b, g1, b1, h1, 224, 224, 32);
  conv_k<32, 8, 8, true, 1><<<dim3(4, 4, 32 * 8), 256, 0, stream>>>(h1, r2w, r2b, g2, b2, h2, 112, 112, 64);
  conv_k<64, 8, 8, true, 1><<<dim3(2, 2, 32 * 16), 256, 0, stream>>>(h2, r3w, r3b, g3, b3, h3, 56, 56, 128);
  conv_k<128, 8, 8, false, 0><<<dim3(1, 1, 32 * 32), 256, 0, stream>>>(h3, rpw, rpb, rpb, rpb, h4, 28, 28, 256);

  // ---- head + NMS ----
  rpn_head_k<<<(32 * NANCH + 255) / 256, 256, 0, stream>>>(h4, clsw, clsb, regw, regb, probs, boxes);
  nms_k<<<32, 256, 0, stream>>>(probs, boxes, dout, hasflag);

  // ---- Stage 2: CLM, batch-chunked by 4, activation aliased onto h1 ----
  constexpr int CHUNK = 4;
  for (int c0 = 0; c0 < 32; c0 += CHUNK) {
    conv_k<4, 4, 8, true, 0><<<dim3(7, 7, CHUNK * 8), 256, 0, stream>>>(
        x + (size_t)c0 * 4 * 224 * 224, c1w, c1b, cg1, cb1, c1buf, 224, 224, 64);
    conv_k<64, 8, 8, true, 2><<<dim3(7, 7, CHUNK * 16), 256, 0, stream>>>(
        c1buf, c2w, c2b, cg2, cb2, pooled + (size_t)c0 * 6272, 224, 224, 128);
  }

  // ---- FC head ----
  fc_k<<<32, 256, 0, stream>>>(pooled, fc1w, fc1b, f1, 6272, 512, 1);
  fc_k<<<32, 256, 0, stream>>>(f1, fc2w, fc2b, f2, 512, 256, 1);
  fc_k<<<32, 256, 0, stream>>>(f2, fc3w, fc3b, f3, 256, 128, 1);
  final_k<<<1, 64, 0, stream>>>(f3, fc4w, fc4b, hasflag, dout);
}

// Round 3
// 2590.667 us; speedup vs baseline: 3.4713x; 3.4713x over previous
//
#include <hip/hip_runtime.h>
#include <math.h>

constexpr int NANCH = 3136;           // 28*28*4
constexpr float SCORE_T = 0.7f;
constexpr float IOU_T = 0.3f;
constexpr int MAXP = 10;

typedef __attribute__((ext_vector_type(8))) short short8x;
typedef __attribute__((ext_vector_type(4))) float f32x4;

__device__ inline unsigned short f2bf(float f) {          // RNE float->bf16
  unsigned u = __builtin_bit_cast(unsigned, f);
  u += 0x7fffu + ((u >> 16) & 1u);
  return (unsigned short)(u >> 16);
}

// =====================================================================
// Generic 3x3 conv, pad=1, NCHW fp32 in. Each block: 32x32 output tile,
// OCB out-channels; 256 threads each own a 2x2 pixel quad.
// MODE 0: +bias(+BN)+ReLU, NCHW fp32 out
// MODE 1: +bias(+BN)+ReLU+2x2 maxpool, NCHW fp32 out (H/2 x W/2)
// MODE 3: +bias+BN+ReLU, NHWC bf16 out (packed 8-cout writes; needs OCB=8,
//         H,W multiples of 32)
// =====================================================================
template<int CIN, int CK, int OCB, bool BN, int MODE>
__global__ __launch_bounds__(256) void conv_k(
    const float* __restrict__ in, const float* __restrict__ wgt,
    const float* __restrict__ bias, const float* __restrict__ gamma,
    const float* __restrict__ beta, float* __restrict__ out,
    int H, int W, int COUT) {
  const int tid = threadIdx.x;
  const int tx = tid & 15, ty = tid >> 4;
  const int ng = COUT / OCB;
  const int b  = blockIdx.z / ng;
  const int oc0 = (blockIdx.z % ng) * OCB;
  __shared__ float s_in[CK][34][34];
  __shared__ float s_w[CK][3][3][OCB];

  float acc[OCB][2][2];
#pragma unroll
  for (int o = 0; o < OCB; o++) {
    acc[o][0][0] = 0.f; acc[o][0][1] = 0.f; acc[o][1][0] = 0.f; acc[o][1][1] = 0.f;
  }
  const int y0 = blockIdx.y * 32 - 1, x0 = blockIdx.x * 32 - 1;

  for (int ck0 = 0; ck0 < CIN; ck0 += CK) {
    for (int t = tid; t < CK * 34 * 34; t += 256) {
      const int ck = t / 1156; const int r = t % 1156;
      const int iy = r / 34, ix = r % 34;
      const int gy = y0 + iy, gx = x0 + ix;
      float v = 0.f;
      if ((unsigned)gy < (unsigned)H && (unsigned)gx < (unsigned)W)
        v = in[(((size_t)b * CIN + ck0 + ck) * H + gy) * W + gx];
      s_in[ck][iy][ix] = v;
    }
    for (int t = tid; t < CK * 9 * OCB; t += 256) {
      const int oc = t % OCB; int r = t / OCB;
      const int kx = r % 3; r /= 3; const int ky = r % 3; const int ck = r / 3;
      s_w[ck][ky][kx][oc] = wgt[(((size_t)(oc0 + oc) * CIN + (ck0 + ck)) * 3 + ky) * 3 + kx];
    }
    __syncthreads();

#pragma unroll 2
    for (int ck = 0; ck < CK; ck++) {
#pragma unroll
      for (int ky = 0; ky < 3; ky++) {
#pragma unroll
        for (int kx = 0; kx < 3; kx++) {
          float w8[OCB];
#pragma unroll
          for (int o = 0; o < OCB; o++) w8[o] = s_w[ck][ky][kx][o];
          float xv[2][2];
#pragma unroll
          for (int dy = 0; dy < 2; dy++)
#pragma unroll
            for (int dx = 0; dx < 2; dx++)
              xv[dy][dx] = s_in[ck][2 * ty + dy + ky][2 * tx + dx + kx];
#pragma unroll
          for (int o = 0; o < OCB; o++)
#pragma unroll
            for (int dy = 0; dy < 2; dy++)
#pragma unroll
              for (int dx = 0; dx < 2; dx++)
                acc[o][dy][dx] = fmaf(w8[o], xv[dy][dx], acc[o][dy][dx]);
        }
      }
    }
    __syncthreads();
  }

  const float rsq = 1.f / sqrtf(1.f + 1e-5f);

  if (MODE == 3) {
    float bi8[OCB], sc8[OCB], sh8[OCB];
#pragma unroll
    for (int o = 0; o < OCB; o++) {
      bi8[o] = bias[oc0 + o];
      sc8[o] = gamma[oc0 + o] * rsq;
      sh8[o] = beta[oc0 + o];
    }
    unsigned short* outb = (unsigned short*)out;
#pragma unroll
    for (int dy = 0; dy < 2; dy++)
#pragma unroll
      for (int dx = 0; dx < 2; dx++) {
        const int oy = blockIdx.y * 32 + 2 * ty + dy;
        const int ox = blockIdx.x * 32 + 2 * tx + dx;
        unsigned short u[8];
#pragma unroll
        for (int o = 0; o < OCB; o++)
          u[o] = f2bf(fmaxf((acc[o][dy][dx] + bi8[o]) * sc8[o] + sh8[o], 0.f));
        *(uint4*)&outb[(((size_t)b * 224 + oy) * 224 + ox) * 64 + oc0] = *(uint4*)u;
      }
    return;
  }

#pragma unroll
  for (int o = 0; o < OCB; o++) {
    const int oc = oc0 + o;
    const float bi = bias[oc];
    float scl = 1.f, shf = 0.f;
    if (BN) { scl = gamma[oc] * rsq; shf = beta[oc]; }

    if (MODE == 0) {
#pragma unroll
      for (int dy = 0; dy < 2; dy++)
#pragma unroll
        for (int dx = 0; dx < 2; dx++) {
          const int oy = blockIdx.y * 32 + 2 * ty + dy;
          const int ox = blockIdx.x * 32 + 2 * tx + dx;
          if (oy < H && ox < W) {
            const float e = (acc[o][dy][dx] + bi) * scl + shf;
            out[(((size_t)b * COUT + oc) * H + oy) * W + ox] = fmaxf(e, 0.f);
          }
        }
    } else if (MODE == 1) {
      const int PH = H >> 1, PW = W >> 1;
      const int py = blockIdx.y * 16 + ty, px = blockIdx.x * 16 + tx;
      if (py < PH && px < PW) {
        float m = (acc[o][0][0] + bi) * scl + shf;
        m = fmaxf(m, (acc[o][0][1] + bi) * scl + shf);
        m = fmaxf(m, (acc[o][1][0] + bi) * scl + shf);
        m = fmaxf(m, (acc[o][1][1] + bi) * scl + shf);
        out[(((size_t)b * COUT + oc) * PH + py) * PW + px] = fmaxf(m, 0.f);
      }
    }
  }
}

// =====================================================================
// c2 weight prep: [128,64,3,3] fp32 -> [9 taps][128 cout][64 cin] bf16
// =====================================================================
__global__ __launch_bounds__(256) void w2b_k(const float* __restrict__ w,
                                             unsigned short* __restrict__ wb) {
  const int i = blockIdx.x * 256 + threadIdx.x;   // 9*128*64 = 73728
  if (i >= 73728) return;
  const int cin = i & 63; const int r = i >> 6;
  const int cout = r & 127; const int tap = r >> 7;
  wb[i] = f2bf(w[(((size_t)cout * 64 + cin) * 3 + tap / 3) * 3 + tap % 3]);
}

// =====================================================================
// CLM conv2 via MFMA implicit GEMM + fused BN/ReLU/avgpool.
// Block: one 32x32 spatial tile (= one 7x7 pool cell) x 128 cout.
// act: [IMGS,224,224,64] bf16 NHWC.  wb: [9][128][64] bf16.
// 8 bands of 4 rows; per band K = 9 taps x 64 cin; waves 2(M)x2(N),
// wave tile 64 px x 64 cout = 4x4 frags of 16x16x32.
// =====================================================================
__global__ __launch_bounds__(256) void c2mfma_k(
    const unsigned short* __restrict__ act, const unsigned short* __restrict__ wb,
    const float* __restrict__ bias, const float* __restrict__ gamma,
    const float* __restrict__ beta, float* __restrict__ pooled) {
  __shared__ unsigned short s_in[6 * 34 * 72];   // rows padded 64->72 (144B, 16B-aligned)
  __shared__ unsigned short s_w[2 * 128 * 40];   // cin-half chunks, rows 32->40 (80B)
  __shared__ float s_pool[128];

  const int tid = threadIdx.x;
  const int lane = tid & 63, wave = tid >> 6;
  const int wm = wave >> 1, wn = wave & 1;
  const int lr = lane & 15, lg = lane >> 4;
  const int img = blockIdx.z;
  const int x0 = blockIdx.x * 32, y0 = blockIdx.y * 32;
  const float rsq = 1.f / sqrtf(1.f + 1e-5f);

  if (tid < 128) s_pool[tid] = 0.f;

  for (int band = 0; band < 8; ++band) {
    __syncthreads();                      // prev band/tap consumers done (also covers s_pool init)
    // ---- stage 6 input rows x 34 cols x 64 cin (zero halo) ----
    for (int idx = tid; idx < 1632; idx += 256) {
      const int r = idx / 272, rem = idx % 272;
      const int c = rem >> 3, q = rem & 7;
      const int gy = y0 + band * 4 - 1 + r, gx = x0 - 1 + c;
      uint4 v = make_uint4(0, 0, 0, 0);
      if ((unsigned)gy < 224u && (unsigned)gx < 224u)
        v = *(const uint4*)(act + (((size_t)img * 224 + gy) * 224 + gx) * 64 + q * 8);
      *(uint4*)(&s_in[(r * 34 + c) * 72 + q * 8]) = v;
    }

    f32x4 acc[4][4];
#pragma unroll
    for (int mi = 0; mi < 4; ++mi)
#pragma unroll
      for (int ni = 0; ni < 4; ++ni) acc[mi][ni] = (f32x4)(0.f);

    for (int tap = 0; tap < 9; ++tap) {
      const int ky = tap / 3, kx = tap % 3;
      // ---- stage weights for this tap: both cin-halves [128][32] ----
      for (int idx = tid; idx < 1024; idx += 256) {
        const int cout = idx >> 3, q = idx & 7;
        uint4 v = *(const uint4*)(wb + ((size_t)tap * 128 + cout) * 64 + q * 8);
        *(uint4*)(&s_w[(q >> 2) * 5120 + cout * 40 + (q & 3) * 8]) = v;
      }
      __syncthreads();
#pragma unroll
      for (int h = 0; h < 2; ++h) {
        short8x a[4], bf[4];
#pragma unroll
        for (int mi = 0; mi < 4; ++mi) {
          const int rl = wm * 2 + (mi >> 1) + ky;            // s_in row
          const int cc = (mi & 1) * 16 + lr + kx;            // s_in col
          a[mi] = *(const short8x*)(&s_in[(rl * 34 + cc) * 72 + h * 32 + lg * 8]);
        }
#pragma unroll
        for (int ni = 0; ni < 4; ++ni) {
          const int co = wn * 64 + ni * 16 + lr;
          bf[ni] = *(const short8x*)(&s_w[h * 5120 + co * 40 + lg * 8]);
        }
#pragma unroll
        for (int mi = 0; mi < 4; ++mi)
#pragma unroll
          for (int ni = 0; ni < 4; ++ni)
            acc[mi][ni] = __builtin_amdgcn_mfma_f32_16x16x32_bf16(a[mi], bf[ni], acc[mi][ni], 0, 0, 0);
      }
      __syncthreads();
    }
    // ---- epilogue: bias+BN+ReLU, pool-accumulate (D: col=lane&15=cout) ----
#pragma unroll
    for (int ni = 0; ni < 4; ++ni) {
      const int co = wn * 64 + ni * 16 + lr;
      const float bi = bias[co], scl = gamma[co] * rsq, shf = beta[co];
      float s = 0.f;
#pragma unroll
      for (int mi = 0; mi < 4; ++mi)
#pragma unroll
        for (int j = 0; j < 4; ++j)
          s += fmaxf((acc[mi][ni][j] + bi) * scl + shf, 0.f);
      atomicAdd(&s_pool[co], s);
    }
  }
  __syncthreads();
  if (tid < 128)
    pooled[(size_t)img * 6272 + tid * 49 + blockIdx.y * 7 + blockIdx.x] =
        s_pool[tid] * (1.f / 1024.f);
}

// =====================================================================
// RPN head: 1x1 cls/reg convs + softmax prob + anchor decode.
// =====================================================================
__global__ __launch_bounds__(256) void rpn_head_k(
    const float* __restrict__ feat,
    const float* __restrict__ clsw, const float* __restrict__ clsb,
    const float* __restrict__ regw, const float* __restrict__ regb,
    float* __restrict__ probs, float* __restrict__ boxes) {
  const int gid = blockIdx.x * 256 + threadIdx.x;
  if (gid >= 32 * NANCH) return;
  const int a = gid & 3;
  int r = gid >> 2;
  const int x = r % 28; r /= 28;
  const int y = r % 28;
  const int b = r / 28;

  const float* f = feat + (size_t)b * 256 * 784 + y * 28 + x;
  float c0 = clsb[2 * a], c1 = clsb[2 * a + 1];
  float r0 = regb[4 * a], r1 = regb[4 * a + 1], r2 = regb[4 * a + 2], r3 = regb[4 * a + 3];
#pragma unroll 4
  for (int c = 0; c < 256; c++) {
    const float fv = f[(size_t)c * 784];
    c0 = fmaf(fv, clsw[(2 * a) * 256 + c], c0);
    c1 = fmaf(fv, clsw[(2 * a + 1) * 256 + c], c1);
    r0 = fmaf(fv, regw[(4 * a) * 256 + c], r0);
    r1 = fmaf(fv, regw[(4 * a + 1) * 256 + c], r1);
    r2 = fmaf(fv, regw[(4 * a + 2) * 256 + c], r2);
    r3 = fmaf(fv, regw[(4 * a + 3) * 256 + c], r3);
  }
  const float p = 1.f / (1.f + expf(c0 - c1));

  const float cx = (x + 0.5f) * (1.f / 28.f);
  const float cy = (y + 0.5f) * (1.f / 28.f);
  const float sz = (float)(16 << a) * (1.f / 224.f);
  const float ncx = cx + r0 * 0.1f, ncy = cy + r1 * 0.1f;
  const float nw = sz * expf(r2 * 0.2f), nh = sz * expf(r3 * 0.2f);
  const float x1 = fminf(fmaxf(ncx - nw * 0.5f, 0.f), 1.f);
  const float y1 = fminf(fmaxf(ncy - nh * 0.5f, 0.f), 1.f);
  const float x2 = fminf(fmaxf(ncx + nw * 0.5f, 0.f), 1.f);
  const float y2 = fminf(fmaxf(ncy + nh * 0.5f, 0.f), 1.f);

  probs[gid] = p;
  ((float4*)boxes)[gid] = make_float4(x1, y1, x2, y2);
}

// =====================================================================
// Greedy NMS, one block per image (matches jax.lax.scan semantics).
// =====================================================================
__global__ __launch_bounds__(256) void nms_k(
    const float* __restrict__ probs, const float* __restrict__ boxes,
    float* __restrict__ dout, int* __restrict__ hasflag) {
  const int b = blockIdx.x;
  const int t = threadIdx.x;
  __shared__ float sc[NANCH];
  __shared__ float ar[NANCH];
  __shared__ float4 bx[NANCH];
  __shared__ float rv[256];
  __shared__ int   ri[256];
  __shared__ int s_any, s_sel[MAXP], s_ok[MAXP];

  if (t == 0) s_any = 0;
  __syncthreads();

  int anyl = 0;
  for (int i = t; i < NANCH; i += 256) {
    const float p = probs[(size_t)b * NANCH + i];
    const float4 bb = ((const float4*)boxes)[(size_t)b * NANCH + i];
    bx[i] = bb;
    ar[i] = (bb.z - bb.x) * (bb.w - bb.y);
    sc[i] = (p > SCORE_T) ? p : -INFINITY;
    if (p > SCORE_T) anyl = 1;
  }
  if (anyl) atomicOr(&s_any, 1);
  __syncthreads();

  for (int it = 0; it < MAXP; ++it) {
    float bv = -INFINITY; int bi = 0x7fffffff;
    for (int i = t; i < NANCH; i += 256) {
      const float v = sc[i];
      if (v > bv || (v == bv && i < bi)) { bv = v; bi = i; }
    }
    rv[t] = bv; ri[t] = bi;
    __syncthreads();
    for (int st = 128; st > 0; st >>= 1) {
      if (t < st) {
        const float ov = rv[t + st]; const int oi = ri[t + st];
        if (ov > rv[t] || (ov == rv[t] && oi < ri[t])) { rv[t] = ov; ri[t] = oi; }
      }
      __syncthreads();
    }
    if (t == 0) { s_sel[it] = ri[0]; s_ok[it] = (rv[0] > -INFINITY) ? 1 : 0; }
    __syncthreads();
    const int sel = s_sel[it];
    const int ok  = s_ok[it];
    if (ok) {
      const float4 bs = bx[sel]; const float as = ar[sel];
      for (int i = t; i < NANCH; i += 256) {
        const float xx1 = fmaxf(bs.x, bx[i].x), yy1 = fmaxf(bs.y, bx[i].y);
        const float xx2 = fminf(bs.z, bx[i].z), yy2 = fminf(bs.w, bx[i].w);
        const float inter = fmaxf(xx2 - xx1, 0.f) * fmaxf(yy2 - yy1, 0.f);
        const float iou = inter / (as + ar[i] - inter);
        if (iou > IOU_T || i == sel) sc[i] = -INFINITY;
      }
    }
    __syncthreads();
  }

  if (t < MAXP) {
    const int sel = s_ok[t] ? s_sel[t] : 0;
    const float okf = s_ok[t] ? 1.f : 0.f;
    const float4 bb = bx[sel];
    float* kb = dout + 64;
    float* ks = dout + 64 + 32 * MAXP * 4;
    float* ko = dout + 64 + 32 * MAXP * 5;
    const size_t base = ((size_t)b * MAXP + t) * 4;
    kb[base + 0] = bb.x * okf; kb[base + 1] = bb.y * okf;
    kb[base + 2] = bb.z * okf; kb[base + 3] = bb.w * okf;
    ks[b * MAXP + t] = probs[(size_t)b * NANCH + sel] * okf;
    ko[b * MAXP + t] = okf;
  }
  if (t == 0) hasflag[b] = s_any;
}

// =====================================================================
// FC split-K: grid (N/64, KT), 64-thread blocks; each block computes
// partial dots for all 32 batch rows x 64 outputs over kchunk of K.
// Weights are read exactly once across the grid.
// =====================================================================
__global__ __launch_bounds__(64) void fcsplit_k(
    const float* __restrict__ x, const float* __restrict__ w,
    float* __restrict__ part, int K, int N, int kchunk) {
  extern __shared__ float sx[];                    // [32 * kchunk]
  const int o = blockIdx.x * 64 + threadIdx.x;
  const int k0 = blockIdx.y * kchunk;
  for (int i = threadIdx.x; i < 32 * kchunk; i += 64) {
    const int bb = i / kchunk, kk = i % kchunk;
    sx[i] = x[(size_t)bb * K + k0 + kk];
  }
  __syncthreads();
  float acc[32];
#pragma unroll
  for (int bb = 0; bb < 32; bb++) acc[bb] = 0.f;
#pragma unroll 8
  for (int kk = 0; kk < kchunk; kk++) {
    const float wv = w[(size_t)(k0 + kk) * N + o];
#pragma unroll
    for (int bb = 0; bb < 32; bb++) acc[bb] = fmaf(sx[bb * kchunk + kk], wv, acc[bb]);
  }
  float* p = part + (size_t)blockIdx.y * 32 * N + o;
#pragma unroll
  for (int bb = 0; bb < 32; bb++) p[(size_t)bb * N] = acc[bb];
}

__global__ __launch_bounds__(256) void fcreduce_k(
    const float* __restrict__ part, const float* __restrict__ bias,
    float* __restrict__ y, int N, int KT, int dorelu) {
  const int i = blockIdx.x * 256 + threadIdx.x;    // over 32*N
  if (i >= 32 * N) return;
  const int o = i % N;
  float s = bias[o];
  for (int kt = 0; kt < KT; kt++) s += part[(size_t)kt * 32 * N + i];
  y[i] = dorelu ? fmaxf(s, 0.f) : s;
}

__global__ __launch_bounds__(64) void final_k(
    const float* __restrict__ f3, const float* __restrict__ w,
    const float* __restrict__ bi, const int* __restrict__ hasflag,
    float* __restrict__ dout) {
  const int t = threadIdx.x;
  if (t >= 64) return;
  const int b = t >> 1, j = t & 1;
  float acc = bi[j];
#pragma unroll 4
  for (int k = 0; k < 128; k++) acc = fmaf(f3[b * 128 + k], w[k * 2 + j], acc);
  dout[b * 2 + j] = hasflag[b] ? acc : (j == 0 ? 1.f : 0.f);
}

// =====================================================================
extern "C" void kernel_launch(void* const* d_in, const int* in_sizes, int n_in,
                              void* d_out, int out_size, void* d_ws, size_t ws_size,
                              hipStream_t stream) {
  const float* x    = (const float*)d_in[0];
  const float* r1w  = (const float*)d_in[1];  const float* r1b = (const float*)d_in[2];
  const float* g1   = (const float*)d_in[3];  const float* b1  = (const float*)d_in[4];
  const float* r2w  = (const float*)d_in[5];  const float* r2b = (const float*)d_in[6];
  const float* g2   = (const float*)d_in[7];  const float* b2  = (const float*)d_in[8];
  const float* r3w  = (const float*)d_in[9];  const float* r3b = (const float*)d_in[10];
  const float* g3   = (const float*)d_in[11]; const float* b3  = (const float*)d_in[12];
  const float* rpw  = (const float*)d_in[13]; const float* rpb = (const float*)d_in[14];
  const float* clsw = (const float*)d_in[15]; const float* clsb = (const float*)d_in[16];
  const float* regw = (const float*)d_in[17]; const float* regb = (const float*)d_in[18];
  const float* c1w  = (const float*)d_in[19]; const float* c1b = (const float*)d_in[20];
  const float* cg1  = (const float*)d_in[21]; const float* cb1 = (const float*)d_in[22];
  const float* c2w  = (const float*)d_in[23]; const float* c2b = (const float*)d_in[24];
  const float* cg2  = (const float*)d_in[25]; const float* cb2 = (const float*)d_in[26];
  const float* fc1w = (const float*)d_in[27]; const float* fc1b = (const float*)d_in[28];
  const float* fc2w = (const float*)d_in[29]; const float* fc2b = (const float*)d_in[30];
  const float* fc3w = (const float*)d_in[31]; const float* fc3b = (const float*)d_in[32];
  const float* fc4w = (const float*)d_in[33]; const float* fc4b = (const float*)d_in[34];
  float* dout = (float*)d_out;
  float* Wp = (float*)d_ws;

  // workspace layout (float slots) — identical footprint to round 2 (~102 MB):
  const size_t o_h1   = 0;                               // [32,32,112,112] = 12,845,056
  const size_t o_h2   = o_h1 + (size_t)32*32*112*112;    // [32,64,56,56]   = 3,211,264
  const size_t o_h3   = o_h2 + (size_t)32*64*56*56;      // [32,128,28,28]  = 802,816
  const size_t o_h4   = o_h3 + (size_t)32*128*28*28;     // [32,256,28,28]  = 6,422,528
  const size_t o_prob = o_h4 + (size_t)32*256*28*28;
  const size_t o_box  = o_prob + (size_t)32*3136;
  const size_t o_flag = o_box + (size_t)32*3136*4;
  const size_t o_pool = o_flag + 32;
  const size_t o_f1   = o_pool + (size_t)32*6272;
  const size_t o_f2   = o_f1 + 32*512;
  const size_t o_f3   = o_f2 + 32*256;

  float* h1 = Wp + o_h1; float* h2 = Wp + o_h2; float* h3 = Wp + o_h3; float* h4 = Wp + o_h4;
  float* probs = Wp + o_prob; float* boxes = Wp + o_box;
  int* hasflag = (int*)(Wp + o_flag);
  float* pooled = Wp + o_pool;
  float* f1 = Wp + o_f1; float* f2 = Wp + o_f2; float* f3 = Wp + o_f3;
  // Aliases (safe by stream order):
  unsigned short* c1buf = (unsigned short*)h1;  // [8,224,224,64] bf16 = 51.4MB == |h1|
  unsigned short* w2b   = (unsigned short*)h3;  // 9*128*64 bf16 (h3 dead after rpn conv)
  float* part = h2;                             // fc split partials (h2 dead after conv3)

  // ---- Stage 1: RPN backbone (fp32, exact) ----
  conv_k<4, 4, 8, true, 1><<<dim3(7, 7, 32 * 4), 256, 0, stream>>>(x,  r1w, r1b, g1, b1, h1, 224, 224, 32);
  conv_k<32, 8, 8, true, 1><<<dim3(4, 4, 32 * 8), 256, 0, stream>>>(h1, r2w, r2b, g2, b2, h2, 112, 112, 64);
  conv_k<64, 8, 8, true, 1><<<dim3(2, 2, 32 * 16), 256, 0, stream>>>(h2, r3w, r3b, g3, b3, h3, 56, 56, 128);
  conv_k<128, 8, 8, false, 0><<<dim3(1, 1, 32 * 32), 256, 0, stream>>>(h3, rpw, rpb, rpb, rpb, h4, 28, 28, 256);

  rpn_head_k<<<(32 * NANCH + 255) / 256, 256, 0, stream>>>(h4, clsw, clsb, regw, regb, probs, boxes);
  nms_k<<<32, 256, 0, stream>>>(probs, boxes, dout, hasflag);

  // ---- Stage 2: CLM (c1 fp32->bf16 NHWC; c2 = MFMA implicit GEMM) ----
  w2b_k<<<288, 256, 0, stream>>>(c2w, w2b);      // after rpn conv: h3 is dead now
  constexpr int CHUNK = 8;
  for (int c0 = 0; c0 < 32; c0 += CHUNK) {
    conv_k<4, 4, 8, true, 3><<<dim3(7, 7, CHUNK * 8), 256, 0, stream>>>(
        x + (size_t)c0 * 4 * 224 * 224, c1w, c1b, cg1, cb1, (float*)c1buf, 224, 224, 64);
    c2mfma_k<<<dim3(7, 7, CHUNK), 256, 0, stream>>>(
        c1buf, w2b, c2b, cg2, cb2, pooled + (size_t)c0 * 6272);
  }

  // ---- FC head: split-K, weights read once ----
  fcsplit_k<<<dim3(8, 64), 64, 32 * 98 * 4, stream>>>(pooled, fc1w, part, 6272, 512, 98);
  fcreduce_k<<<64, 256, 0, stream>>>(part, fc1b, f1, 512, 64, 1);
  fcsplit_k<<<dim3(4, 16), 64, 32 * 32 * 4, stream>>>(f1, fc2w, part, 512, 256, 32);
  fcreduce_k<<<32, 256, 0, stream>>>(part, fc2b, f2, 256, 16, 1);
  fcsplit_k<<<dim3(2, 8), 64, 32 * 32 * 4, stream>>>(f2, fc3w, part, 256, 128, 32);
  fcreduce_k<<<16, 256, 0, stream>>>(part, fc3b, f3, 128, 8, 1);
  final_k<<<1, 64, 0, stream>>>(f3, fc4w, fc4b, hasflag, dout);
}

// Round 5
// 1339.583 us; speedup vs baseline: 6.7134x; 1.9339x over previous
//
#include <hip/hip_runtime.h>
#include <math.h>

constexpr int NANCH = 3136;           // 28*28*4
constexpr float SCORE_T = 0.7f;
constexpr float IOU_T = 0.3f;
constexpr int MAXP = 10;

typedef unsigned short u16;
typedef __attribute__((ext_vector_type(8))) short short8x;
typedef __attribute__((ext_vector_type(4))) float f32x4;

__device__ inline u16 f2bf(float f) {          // RNE float->bf16
  unsigned u = __builtin_bit_cast(unsigned, f);
  u += 0x7fffu + ((u >> 16) & 1u);
  return (u16)(u >> 16);
}
__device__ inline float bf2f(u16 h) {
  unsigned u = ((unsigned)h) << 16;
  return __builtin_bit_cast(float, u);
}

// =====================================================================
// Generic 3x3 conv, pad=1, NCHW fp32 in (vector-ALU path, exact fp32).
// MODE 0: +bias(+BN)+ReLU, NCHW fp32 out
// MODE 1: +bias(+BN)+ReLU+2x2 maxpool, NCHW fp32 out
// MODE 3: +bias+BN+ReLU, NHWC bf16 out (single plane, CLM c1; OCB=8)
// MODE 5: +bias+BN+ReLU+2x2 maxpool, NHWC split hi/lo bf16 out (OCB=8)
// =====================================================================
template<int CIN, int CK, int OCB, bool BN, int MODE>
__global__ __launch_bounds__(256) void conv_k(
    const float* __restrict__ in, const float* __restrict__ wgt,
    const float* __restrict__ bias, const float* __restrict__ gamma,
    const float* __restrict__ beta, float* __restrict__ out,
    u16* __restrict__ o2hi, u16* __restrict__ o2lo,
    int H, int W, int COUT) {
  const int tid = threadIdx.x;
  const int tx = tid & 15, ty = tid >> 4;
  const int ng = COUT / OCB;
  const int b  = blockIdx.z / ng;
  const int oc0 = (blockIdx.z % ng) * OCB;
  __shared__ float s_in[CK][34][34];
  __shared__ float s_w[CK][3][3][OCB];

  float acc[OCB][2][2];
#pragma unroll
  for (int o = 0; o < OCB; o++) {
    acc[o][0][0] = 0.f; acc[o][0][1] = 0.f; acc[o][1][0] = 0.f; acc[o][1][1] = 0.f;
  }
  const int y0 = blockIdx.y * 32 - 1, x0 = blockIdx.x * 32 - 1;

  for (int ck0 = 0; ck0 < CIN; ck0 += CK) {
    for (int t = tid; t < CK * 34 * 34; t += 256) {
      const int ck = t / 1156; const int r = t % 1156;
      const int iy = r / 34, ix = r % 34;
      const int gy = y0 + iy, gx = x0 + ix;
      float v = 0.f;
      if ((unsigned)gy < (unsigned)H && (unsigned)gx < (unsigned)W)
        v = in[(((size_t)b * CIN + ck0 + ck) * H + gy) * W + gx];
      s_in[ck][iy][ix] = v;
    }
    for (int t = tid; t < CK * 9 * OCB; t += 256) {
      const int oc = t % OCB; int r = t / OCB;
      const int kx = r % 3; r /= 3; const int ky = r % 3; const int ck = r / 3;
      s_w[ck][ky][kx][oc] = wgt[(((size_t)(oc0 + oc) * CIN + (ck0 + ck)) * 3 + ky) * 3 + kx];
    }
    __syncthreads();

#pragma unroll 2
    for (int ck = 0; ck < CK; ck++) {
#pragma unroll
      for (int ky = 0; ky < 3; ky++) {
#pragma unroll
        for (int kx = 0; kx < 3; kx++) {
          float w8[OCB];
#pragma unroll
          for (int o = 0; o < OCB; o++) w8[o] = s_w[ck][ky][kx][o];
          float xv[2][2];
#pragma unroll
          for (int dy = 0; dy < 2; dy++)
#pragma unroll
            for (int dx = 0; dx < 2; dx++)
              xv[dy][dx] = s_in[ck][2 * ty + dy + ky][2 * tx + dx + kx];
#pragma unroll
          for (int o = 0; o < OCB; o++)
#pragma unroll
            for (int dy = 0; dy < 2; dy++)
#pragma unroll
              for (int dx = 0; dx < 2; dx++)
                acc[o][dy][dx] = fmaf(w8[o], xv[dy][dx], acc[o][dy][dx]);
        }
      }
    }
    __syncthreads();
  }

  const float rsq = 1.f / sqrtf(1.f + 1e-5f);

  if (MODE == 3) {   // NHWC bf16 single plane (CLM c1)
    float bi8[OCB], sc8[OCB], sh8[OCB];
#pragma unroll
    for (int o = 0; o < OCB; o++) {
      bi8[o] = bias[oc0 + o]; sc8[o] = gamma[oc0 + o] * rsq; sh8[o] = beta[oc0 + o];
    }
#pragma unroll
    for (int dy = 0; dy < 2; dy++)
#pragma unroll
      for (int dx = 0; dx < 2; dx++) {
        const int oy = blockIdx.y * 32 + 2 * ty + dy;
        const int ox = blockIdx.x * 32 + 2 * tx + dx;
        u16 u[8];
#pragma unroll
        for (int o = 0; o < OCB; o++)
          u[o] = f2bf(fmaxf((acc[o][dy][dx] + bi8[o]) * sc8[o] + sh8[o], 0.f));
        *(uint4*)&o2hi[(((size_t)b * 224 + oy) * 224 + ox) * 64 + oc0] = *(uint4*)u;
      }
    return;
  }

  if (MODE == 5) {   // pooled NHWC hi/lo (RPN conv1)
    const int PH = H >> 1, PW = W >> 1;
    const int py = blockIdx.y * 16 + ty, px = blockIdx.x * 16 + tx;
    u16 uh[8], ul[8];
#pragma unroll
    for (int o = 0; o < OCB; o++) {
      const int oc = oc0 + o;
      const float bi = bias[oc], scl = gamma[oc] * rsq, shf = beta[oc];
      float m = (acc[o][0][0] + bi) * scl + shf;
      m = fmaxf(m, (acc[o][0][1] + bi) * scl + shf);
      m = fmaxf(m, (acc[o][1][0] + bi) * scl + shf);
      m = fmaxf(m, (acc[o][1][1] + bi) * scl + shf);
      m = fmaxf(m, 0.f);
      uh[o] = f2bf(m); ul[o] = f2bf(m - bf2f(uh[o]));
    }
    const size_t base = (((size_t)b * PH + py) * PW + px) * 32 + oc0;
    *(uint4*)&o2hi[base] = *(uint4*)uh;
    *(uint4*)&o2lo[base] = *(uint4*)ul;
    return;
  }

#pragma unroll
  for (int o = 0; o < OCB; o++) {
    const int oc = oc0 + o;
    const float bi = bias[oc];
    float scl = 1.f, shf = 0.f;
    if (BN) { scl = gamma[oc] * rsq; shf = beta[oc]; }

    if (MODE == 0) {
#pragma unroll
      for (int dy = 0; dy < 2; dy++)
#pragma unroll
        for (int dx = 0; dx < 2; dx++) {
          const int oy = blockIdx.y * 32 + 2 * ty + dy;
          const int ox = blockIdx.x * 32 + 2 * tx + dx;
          if (oy < H && ox < W) {
            const float e = (acc[o][dy][dx] + bi) * scl + shf;
            out[(((size_t)b * COUT + oc) * H + oy) * W + ox] = fmaxf(e, 0.f);
          }
        }
    } else if (MODE == 1) {
      const int PH = H >> 1, PW = W >> 1;
      const int py = blockIdx.y * 16 + ty, px = blockIdx.x * 16 + tx;
      if (py < PH && px < PW) {
        float m = (acc[o][0][0] + bi) * scl + shf;
        m = fmaxf(m, (acc[o][0][1] + bi) * scl + shf);
        m = fmaxf(m, (acc[o][1][0] + bi) * scl + shf);
        m = fmaxf(m, (acc[o][1][1] + bi) * scl + shf);
        out[(((size_t)b * COUT + oc) * PH + py) * PW + px] = fmaxf(m, 0.f);
      }
    }
  }
}

// =====================================================================
// Weight prep: [COUT][CIN][3][3] fp32 -> [tap][cout][cin] bf16 hi/lo planes
// =====================================================================
__global__ __launch_bounds__(256) void wsplit_k(const float* __restrict__ w,
                                                u16* __restrict__ hi, u16* __restrict__ lo,
                                                int COUT, int CIN) {
  const int n = 9 * COUT * CIN;
  const int i = blockIdx.x * 256 + threadIdx.x;
  if (i >= n) return;
  const int cin = i % CIN; int r = i / CIN;
  const int cout = r % COUT; const int tap = r / COUT;
  const float v = w[((size_t)cout * CIN + cin) * 9 + tap];
  const u16 h = f2bf(v);
  hi[i] = h; lo[i] = f2bf(v - bf2f(h));
}

// single-plane bf16 prep for CLM c2: [128,64,3,3] -> [tap][128][64]
__global__ __launch_bounds__(256) void w2b_k(const float* __restrict__ w,
                                             u16* __restrict__ wb) {
  const int i = blockIdx.x * 256 + threadIdx.x;   // 73728
  if (i >= 73728) return;
  const int cin = i & 63; const int r = i >> 6;
  const int cout = r & 127; const int tap = r >> 7;
  wb[i] = f2bf(w[(((size_t)cout * 64 + cin) * 3 + tap / 3) * 3 + tap % 3]);
}

// =====================================================================
// Split-bf16 MFMA 3x3 conv (fp32-accurate via hi/lo x hi/lo, 3 products).
// Input NHWC hi/lo planes. Block: 4-row x 32-col band, 64 couts.
// Waves 2(M:2rows)x2(N:32couts); per-wave acc 4x2 frags of 16x16x32.
// POOL: fused BN+ReLU+2x2 maxpool, NHWC hi/lo out.
// !POOL: +bias+ReLU, NHWC fp32 out (rpn final conv).
// =====================================================================
template<int CINCH, bool POOL, bool BN>
__global__ __launch_bounds__(256) void sconv_k(
    const u16* __restrict__ ahi, const u16* __restrict__ alo,
    const u16* __restrict__ whi, const u16* __restrict__ wlo,
    const float* __restrict__ bias, const float* __restrict__ gamma,
    const float* __restrict__ beta,
    u16* __restrict__ ohi, u16* __restrict__ olo, float* __restrict__ of32,
    int H, int W, int COUT, int cog) {
  __shared__ u16 s_in[6 * 34 * 72];   // [row][col][hi32|lo32], col stride 72
  __shared__ u16 s_w[64 * 72];        // [cout][hi32|lo32]
  const int tid = threadIdx.x, lane = tid & 63, wave = tid >> 6;
  const int wm = wave >> 1, wn = wave & 1, lr = lane & 15, lg = lane >> 4;
  const int img = blockIdx.z / cog, co0 = (blockIdx.z % cog) * 64;
  const int x0 = blockIdx.x * 32, band = blockIdx.y;
  const int CIN = CINCH * 32;

  f32x4 acc[4][2];
#pragma unroll
  for (int mi = 0; mi < 4; ++mi) { acc[mi][0] = (f32x4)(0.f); acc[mi][1] = (f32x4)(0.f); }

  for (int cc2 = 0; cc2 < CINCH; ++cc2) {
    // stage 6 rows x 34 cols x (32hi + 32lo) cin
    for (int idx = tid; idx < 1632; idx += 256) {
      const int r = idx / 272, rem = idx % 272;
      const int c = rem >> 3, q = rem & 7, pl = q >> 2, qq = q & 3;
      const int gy = band * 4 - 1 + r, gx = x0 - 1 + c;
      uint4 v = make_uint4(0, 0, 0, 0);
      if ((unsigned)gy < (unsigned)H && (unsigned)gx < (unsigned)W) {
        const u16* src = pl ? alo : ahi;
        v = *(const uint4*)(src + ((size_t)(img * H + gy) * W + gx) * CIN + cc2 * 32 + qq * 8);
      }
      *(uint4*)(&s_in[(r * 34 + c) * 72 + pl * 32 + qq * 8]) = v;
    }
    for (int tap = 0; tap < 9; ++tap) {
      const int ky = tap / 3, kx = tap % 3;
      for (int idx = tid; idx < 512; idx += 256) {
        const int cout = idx >> 3, q = idx & 7, pl = q >> 2, qq = q & 3;
        const u16* src = pl ? wlo : whi;
        uint4 v = *(const uint4*)(src + ((size_t)tap * COUT + co0 + cout) * CIN + cc2 * 32 + qq * 8);
        *(uint4*)(&s_w[cout * 72 + pl * 32 + qq * 8]) = v;
      }
      __syncthreads();
      short8x ah[4], al[4], bh[2], bl[2];
#pragma unroll
      for (int mi = 0; mi < 4; ++mi) {
        const int base = ((2 * wm + (mi >> 1) + ky) * 34 + (mi & 1) * 16 + lr + kx) * 72;
        ah[mi] = *(const short8x*)(&s_in[base + lg * 8]);
        al[mi] = *(const short8x*)(&s_in[base + 32 + lg * 8]);
      }
#pragma unroll
      for (int ni = 0; ni < 2; ++ni) {
        const int wb2 = (wn * 32 + ni * 16 + lr) * 72;
        bh[ni] = *(const short8x*)(&s_w[wb2 + lg * 8]);
        bl[ni] = *(const short8x*)(&s_w[wb2 + 32 + lg * 8]);
      }
#pragma unroll
      for (int mi = 0; mi < 4; ++mi)
#pragma unroll
        for (int ni = 0; ni < 2; ++ni) {
          acc[mi][ni] = __builtin_amdgcn_mfma_f32_16x16x32_bf16(al[mi], bh[ni], acc[mi][ni], 0, 0, 0);
          acc[mi][ni] = __builtin_amdgcn_mfma_f32_16x16x32_bf16(ah[mi], bl[ni], acc[mi][ni], 0, 0, 0);
          acc[mi][ni] = __builtin_amdgcn_mfma_f32_16x16x32_bf16(ah[mi], bh[ni], acc[mi][ni], 0, 0, 0);
        }
      __syncthreads();
    }
  }

  const float rsq = 1.f / sqrtf(1.f + 1e-5f);
#pragma unroll
  for (int ni = 0; ni < 2; ++ni) {
    const int cout = co0 + wn * 32 + ni * 16 + lr;
    const float bi = bias[cout];
    const float scl = BN ? gamma[cout] * rsq : 1.f;
    const float shf = BN ? beta[cout] : 0.f;
    if (POOL) {
      const int OH = H >> 1, OW = W >> 1;
      const int py = band * 2 + wm;
#pragma unroll
      for (int ch = 0; ch < 2; ++ch)
#pragma unroll
        for (int jp = 0; jp < 2; ++jp) {
          float m = (acc[ch][ni][2 * jp] + bi) * scl + shf;
          m = fmaxf(m, (acc[ch][ni][2 * jp + 1] + bi) * scl + shf);
          m = fmaxf(m, (acc[ch + 2][ni][2 * jp] + bi) * scl + shf);
          m = fmaxf(m, (acc[ch + 2][ni][2 * jp + 1] + bi) * scl + shf);
          m = fmaxf(m, 0.f);
          const int px = (x0 >> 1) + ch * 8 + lg * 2 + jp;
          if (px < OW) {
            const size_t o = ((size_t)(img * OH + py) * OW + px) * COUT + cout;
            const u16 h = f2bf(m);
            ohi[o] = h; olo[o] = f2bf(m - bf2f(h));
          }
        }
    } else {
#pragma unroll
      for (int mi = 0; mi < 4; ++mi) {
        const int row = band * 4 + 2 * wm + (mi >> 1);
#pragma unroll
        for (int j = 0; j < 4; ++j) {
          const int px = x0 + (mi & 1) * 16 + lg * 4 + j;
          if (px < W)
            of32[((size_t)(img * H + row) * W + px) * COUT + cout] =
                fmaxf(acc[mi][ni][j] + bi, 0.f);
        }
      }
    }
  }
}

// =====================================================================
// CLM conv2 MFMA, band-per-block: one 4-row band of a 32x32 pool tile,
// all 128 couts. Pool partial -> global atomicAdd (pooled pre-zeroed).
// =====================================================================
__global__ __launch_bounds__(256) void c2band_k(
    const u16* __restrict__ act, const u16* __restrict__ wb,
    const float* __restrict__ bias, const float* __restrict__ gamma,
    const float* __restrict__ beta, float* __restrict__ pooled, int gimg0) {
  __shared__ u16 s_in[6 * 34 * 72];
  __shared__ u16 s_w[2 * 128 * 40];
  __shared__ float s_pool[128];

  const int tid = threadIdx.x;
  const int lane = tid & 63, wave = tid >> 6;
  const int wm = wave >> 1, wn = wave & 1;
  const int lr = lane & 15, lg = lane >> 4;
  const int img = blockIdx.z >> 3, band = blockIdx.z & 7;
  const int x0 = blockIdx.x * 32, y0 = blockIdx.y * 32;
  const float rsq = 1.f / sqrtf(1.f + 1e-5f);

  if (tid < 128) s_pool[tid] = 0.f;

  for (int idx = tid; idx < 1632; idx += 256) {
    const int r = idx / 272, rem = idx % 272;
    const int c = rem >> 3, q = rem & 7;
    const int gy = y0 + band * 4 - 1 + r, gx = x0 - 1 + c;
    uint4 v = make_uint4(0, 0, 0, 0);
    if ((unsigned)gy < 224u && (unsigned)gx < 224u)
      v = *(const uint4*)(act + (((size_t)img * 224 + gy) * 224 + gx) * 64 + q * 8);
    *(uint4*)(&s_in[(r * 34 + c) * 72 + q * 8]) = v;
  }

  f32x4 acc[4][4];
#pragma unroll
  for (int mi = 0; mi < 4; ++mi)
#pragma unroll
    for (int ni = 0; ni < 4; ++ni) acc[mi][ni] = (f32x4)(0.f);

  for (int tap = 0; tap < 9; ++tap) {
    const int ky = tap / 3, kx = tap % 3;
    for (int idx = tid; idx < 1024; idx += 256) {
      const int cout = idx >> 3, q = idx & 7;
      uint4 v = *(const uint4*)(wb + ((size_t)tap * 128 + cout) * 64 + q * 8);
      *(uint4*)(&s_w[(q >> 2) * 5120 + cout * 40 + (q & 3) * 8]) = v;
    }
    __syncthreads();
#pragma unroll
    for (int h = 0; h < 2; ++h) {
      short8x a[4], bf[4];
#pragma unroll
      for (int mi = 0; mi < 4; ++mi) {
        const int rl = wm * 2 + (mi >> 1) + ky;
        const int cc = (mi & 1) * 16 + lr + kx;
        a[mi] = *(const short8x*)(&s_in[(rl * 34 + cc) * 72 + h * 32 + lg * 8]);
      }
#pragma unroll
      for (int ni = 0; ni < 4; ++ni) {
        const int co = wn * 64 + ni * 16 + lr;
        bf[ni] = *(const short8x*)(&s_w[h * 5120 + co * 40 + lg * 8]);
      }
#pragma unroll
      for (int mi = 0; mi < 4; ++mi)
#pragma unroll
        for (int ni = 0; ni < 4; ++ni)
          acc[mi][ni] = __builtin_amdgcn_mfma_f32_16x16x32_bf16(a[mi], bf[ni], acc[mi][ni], 0, 0, 0);
    }
    __syncthreads();
  }
#pragma unroll
  for (int ni = 0; ni < 4; ++ni) {
    const int co = wn * 64 + ni * 16 + lr;
    const float bi = bias[co], scl = gamma[co] * rsq, shf = beta[co];
    float s = 0.f;
#pragma unroll
    for (int mi = 0; mi < 4; ++mi)
#pragma unroll
      for (int j = 0; j < 4; ++j)
        s += fmaxf((acc[mi][ni][j] + bi) * scl + shf, 0.f);
    atomicAdd(&s_pool[co], s);
  }
  __syncthreads();
  if (tid < 128)
    atomicAdd(&pooled[(size_t)(gimg0 + img) * 6272 + tid * 49 + blockIdx.y * 7 + blockIdx.x],
              s_pool[tid] * (1.f / 1024.f));
}

// =====================================================================
// RPN head: feat NHWC [B,784,256]. 1x1 cls/reg + softmax + decode.
// =====================================================================
__global__ __launch_bounds__(256) void rpn_head_k(
    const float* __restrict__ feat,
    const float* __restrict__ clsw, const float* __restrict__ clsb,
    const float* __restrict__ regw, const float* __restrict__ regb,
    float* __restrict__ probs, float* __restrict__ boxes) {
  const int gid = blockIdx.x * 256 + threadIdx.x;
  if (gid >= 32 * NANCH) return;
  const int a = gid & 3;
  int r = gid >> 2;
  const int x = r % 28; r /= 28;
  const int y = r % 28;
  const int b = r / 28;

  const float* f = feat + ((size_t)b * 784 + y * 28 + x) * 256;
  float c0 = clsb[2 * a], c1 = clsb[2 * a + 1];
  float r0 = regb[4 * a], r1 = regb[4 * a + 1], r2 = regb[4 * a + 2], r3 = regb[4 * a + 3];
#pragma unroll 4
  for (int c = 0; c < 256; c++) {
    const float fv = f[c];
    c0 = fmaf(fv, clsw[(2 * a) * 256 + c], c0);
    c1 = fmaf(fv, clsw[(2 * a + 1) * 256 + c], c1);
    r0 = fmaf(fv, regw[(4 * a) * 256 + c], r0);
    r1 = fmaf(fv, regw[(4 * a + 1) * 256 + c], r1);
    r2 = fmaf(fv, regw[(4 * a + 2) * 256 + c], r2);
    r3 = fmaf(fv, regw[(4 * a + 3) * 256 + c], r3);
  }
  const float p = 1.f / (1.f + expf(c0 - c1));

  const float cx = (x + 0.5f) * (1.f / 28.f);
  const float cy = (y + 0.5f) * (1.f / 28.f);
  const float sz = (float)(16 << a) * (1.f / 224.f);
  const float ncx = cx + r0 * 0.1f, ncy = cy + r1 * 0.1f;
  const float nw = sz * expf(r2 * 0.2f), nh = sz * expf(r3 * 0.2f);
  const float x1 = fminf(fmaxf(ncx - nw * 0.5f, 0.f), 1.f);
  const float y1 = fminf(fmaxf(ncy - nh * 0.5f, 0.f), 1.f);
  const float x2 = fminf(fmaxf(ncx + nw * 0.5f, 0.f), 1.f);
  const float y2 = fminf(fmaxf(ncy + nh * 0.5f, 0.f), 1.f);

  probs[gid] = p;
  ((float4*)boxes)[gid] = make_float4(x1, y1, x2, y2);
}

// =====================================================================
// Greedy NMS, one block per image (matches jax.lax.scan semantics).
// =====================================================================
__global__ __launch_bounds__(256) void nms_k(
    const float* __restrict__ probs, const float* __restrict__ boxes,
    float* __restrict__ dout, int* __restrict__ hasflag) {
  const int b = blockIdx.x;
  const int t = threadIdx.x;
  __shared__ float sc[NANCH];
  __shared__ float ar[NANCH];
  __shared__ float4 bx[NANCH];
  __shared__ float rv[256];
  __shared__ int   ri[256];
  __shared__ int s_any, s_sel[MAXP], s_ok[MAXP];

  if (t == 0) s_any = 0;
  __syncthreads();

  int anyl = 0;
  for (int i = t; i < NANCH; i += 256) {
    const float p = probs[(size_t)b * NANCH + i];
    const float4 bb = ((const float4*)boxes)[(size_t)b * NANCH + i];
    bx[i] = bb;
    ar[i] = (bb.z - bb.x) * (bb.w - bb.y);
    sc[i] = (p > SCORE_T) ? p : -INFINITY;
    if (p > SCORE_T) anyl = 1;
  }
  if (anyl) atomicOr(&s_any, 1);
  __syncthreads();

  for (int it = 0; it < MAXP; ++it) {
    float bv = -INFINITY; int bi = 0x7fffffff;
    for (int i = t; i < NANCH; i += 256) {
      const float v = sc[i];
      if (v > bv || (v == bv && i < bi)) { bv = v; bi = i; }
    }
    rv[t] = bv; ri[t] = bi;
    __syncthreads();
    for (int st = 128; st > 0; st >>= 1) {
      if (t < st) {
        const float ov = rv[t + st]; const int oi = ri[t + st];
        if (ov > rv[t] || (ov == rv[t] && oi < ri[t])) { rv[t] = ov; ri[t] = oi; }
      }
      __syncthreads();
    }
    if (t == 0) { s_sel[it] = ri[0]; s_ok[it] = (rv[0] > -INFINITY) ? 1 : 0; }
    __syncthreads();
    const int sel = s_sel[it];
    const int ok  = s_ok[it];
    if (ok) {
      const float4 bs = bx[sel]; const float as = ar[sel];
      for (int i = t; i < NANCH; i += 256) {
        const float xx1 = fmaxf(bs.x, bx[i].x), yy1 = fmaxf(bs.y, bx[i].y);
        const float xx2 = fminf(bs.z, bx[i].z), yy2 = fminf(bs.w, bx[i].w);
        const float inter = fmaxf(xx2 - xx1, 0.f) * fmaxf(yy2 - yy1, 0.f);
        const float iou = inter / (as + ar[i] - inter);
        if (iou > IOU_T || i == sel) sc[i] = -INFINITY;
      }
    }
    __syncthreads();
  }

  if (t < MAXP) {
    const int sel = s_ok[t] ? s_sel[t] : 0;
    const float okf = s_ok[t] ? 1.f : 0.f;
    const float4 bb = bx[sel];
    float* kb = dout + 64;
    float* ks = dout + 64 + 32 * MAXP * 4;
    float* ko = dout + 64 + 32 * MAXP * 5;
    const size_t base = ((size_t)b * MAXP + t) * 4;
    kb[base + 0] = bb.x * okf; kb[base + 1] = bb.y * okf;
    kb[base + 2] = bb.z * okf; kb[base + 3] = bb.w * okf;
    ks[b * MAXP + t] = probs[(size_t)b * NANCH + sel] * okf;
    ko[b * MAXP + t] = okf;
  }
  if (t == 0) hasflag[b] = s_any;
}

// =====================================================================
// FC split-K: weights read exactly once across the grid.
// =====================================================================
__global__ __launch_bounds__(64) void fcsplit_k(
    const float* __restrict__ x, const float* __restrict__ w,
    float* __restrict__ part, int K, int N, int kchunk) {
  extern __shared__ float sx[];
  const int o = blockIdx.x * 64 + threadIdx.x;
  const int k0 = blockIdx.y * kchunk;
  for (int i = threadIdx.x; i < 32 * kchunk; i += 64) {
    const int bb = i / kchunk, kk = i % kchunk;
    sx[i] = x[(size_t)bb * K + k0 + kk];
  }
  __syncthreads();
  float acc[32];
#pragma unroll
  for (int bb = 0; bb < 32; bb++) acc[bb] = 0.f;
#pragma unroll 8
  for (int kk = 0; kk < kchunk; kk++) {
    const float wv = w[(size_t)(k0 + kk) * N + o];
#pragma unroll
    for (int bb = 0; bb < 32; bb++) acc[bb] = fmaf(sx[bb * kchunk + kk], wv, acc[bb]);
  }
  float* p = part + (size_t)blockIdx.y * 32 * N + o;
#pragma unroll
  for (int bb = 0; bb < 32; bb++) p[(size_t)bb * N] = acc[bb];
}

__global__ __launch_bounds__(256) void fcreduce_k(
    const float* __restrict__ part, const float* __restrict__ bias,
    float* __restrict__ y, int N, int KT, int dorelu) {
  const int i = blockIdx.x * 256 + threadIdx.x;
  if (i >= 32 * N) return;
  const int o = i % N;
  float s = bias[o];
  for (int kt = 0; kt < KT; kt++) s += part[(size_t)kt * 32 * N + i];
  y[i] = dorelu ? fmaxf(s, 0.f) : s;
}

__global__ __launch_bounds__(64) void final_k(
    const float* __restrict__ f3, const float* __restrict__ w,
    const float* __restrict__ bi, const int* __restrict__ hasflag,
    float* __restrict__ dout) {
  const int t = threadIdx.x;
  if (t >= 64) return;
  const int b = t >> 1, j = t & 1;
  float acc = bi[j];
#pragma unroll 4
  for (int k = 0; k < 128; k++) acc = fmaf(f3[b * 128 + k], w[k * 2 + j], acc);
  dout[b * 2 + j] = hasflag[b] ? acc : (j == 0 ? 1.f : 0.f);
}

// =====================================================================
extern "C" void kernel_launch(void* const* d_in, const int* in_sizes, int n_in,
                              void* d_out, int out_size, void* d_ws, size_t ws_size,
                              hipStream_t stream) {
  const float* x    = (const float*)d_in[0];
  const float* r1w  = (const float*)d_in[1];  const float* r1b = (const float*)d_in[2];
  const float* g1   = (const float*)d_in[3];  const float* b1  = (const float*)d_in[4];
  const float* r2w  = (const float*)d_in[5];  const float* r2b = (const float*)d_in[6];
  const float* g2   = (const float*)d_in[7];  const float* b2  = (const float*)d_in[8];
  const float* r3w  = (const float*)d_in[9];  const float* r3b = (const float*)d_in[10];
  const float* g3   = (const float*)d_in[11]; const float* b3  = (const float*)d_in[12];
  const float* rpw  = (const float*)d_in[13]; const float* rpb = (const float*)d_in[14];
  const float* clsw = (const float*)d_in[15]; const float* clsb = (const float*)d_in[16];
  const float* regw = (const float*)d_in[17]; const float* regb = (const float*)d_in[18];
  const float* c1w  = (const float*)d_in[19]; const float* c1b = (const float*)d_in[20];
  const float* cg1  = (const float*)d_in[21]; const float* cb1 = (const float*)d_in[22];
  const float* c2w  = (const float*)d_in[23]; const float* c2b = (const float*)d_in[24];
  const float* cg2  = (const float*)d_in[25]; const float* cb2 = (const float*)d_in[26];
  const float* fc1w = (const float*)d_in[27]; const float* fc1b = (const float*)d_in[28];
  const float* fc2w = (const float*)d_in[29]; const float* fc2b = (const float*)d_in[30];
  const float* fc3w = (const float*)d_in[31]; const float* fc3b = (const float*)d_in[32];
  const float* fc4w = (const float*)d_in[33]; const float* fc4b = (const float*)d_in[34];
  float* dout = (float*)d_out;
  float* Wp = (float*)d_ws;

  // ---- workspace layout (float slots), total ~23.6M floats = 94.5 MB ----
  const size_t o_h1   = 0;                      // hi/lo NHWC 32x112x112x32: 2x12.85M shorts
  const size_t o_h2   = 12845056;               // hi/lo NHWC 32x56x56x64
  const size_t o_h3   = o_h2 + 6422528;         // hi/lo NHWC 32x28x28x128
  const size_t o_prob = o_h3 + 3211264;
  const size_t o_box  = o_prob + 100352;
  const size_t o_flag = o_box + 401408;
  const size_t o_pool = o_flag + 32;
  const size_t o_f1   = o_pool + 200704;
  const size_t o_f2   = o_f1 + 16384;
  const size_t o_f3   = o_f2 + 8192;
  const size_t o_w2b  = o_f3 + 4096;            // 73728 shorts (CLM c2 bf16)
  const size_t o_w2s  = o_w2b + 36864;          // conv2 hi+lo: 2x18432 shorts
  const size_t o_w3s  = o_w2s + 18432;          // conv3 hi+lo: 2x73728 shorts
  const size_t o_wps  = o_w3s + 73728;          // rpw  hi+lo: 2x294912 shorts

  u16* h1hi = (u16*)(Wp + o_h1); u16* h1lo = h1hi + 12845056;
  u16* h2hi = (u16*)(Wp + o_h2); u16* h2lo = h2hi + 6422528;
  u16* h3hi = (u16*)(Wp + o_h3); u16* h3lo = h3hi + 3211264;
  float* probs = Wp + o_prob; float* boxes = Wp + o_box;
  int* hasflag = (int*)(Wp + o_flag);
  float* pooled = Wp + o_pool;
  float* f1 = Wp + o_f1; float* f2 = Wp + o_f2; float* f3 = Wp + o_f3;
  u16* w2b  = (u16*)(Wp + o_w2b);
  u16* w2hi = (u16*)(Wp + o_w2s); u16* w2lo = w2hi + 18432;
  u16* w3hi = (u16*)(Wp + o_w3s); u16* w3lo = w3hi + 73728;
  u16* wphi = (u16*)(Wp + o_wps); u16* wplo = wphi + 294912;
  // aliases over dead h1 region (safe by stream order):
  float* h4f32 = Wp + o_h1;            // rpn feat NHWC fp32 [32,784,256] = 6.42M
  u16*   c1buf = (u16*)(Wp + o_h1);    // CLM c1 NHWC bf16, 8 imgs = 25.69M shorts
  float* fcpart = Wp + o_h1;           // fc split partials (<= 1.05M)

  // ---- weight prep ----
  wsplit_k<<<(9 * 64 * 32 + 255) / 256, 256, 0, stream>>>(r2w, w2hi, w2lo, 64, 32);
  wsplit_k<<<(9 * 128 * 64 + 255) / 256, 256, 0, stream>>>(r3w, w3hi, w3lo, 128, 64);
  wsplit_k<<<(9 * 256 * 128 + 255) / 256, 256, 0, stream>>>(rpw, wphi, wplo, 256, 128);
  w2b_k<<<288, 256, 0, stream>>>(c2w, w2b);

  // ---- Stage 1: RPN backbone ----
  conv_k<4, 4, 8, true, 5><<<dim3(7, 7, 32 * 4), 256, 0, stream>>>(
      x, r1w, r1b, g1, b1, Wp, h1hi, h1lo, 224, 224, 32);
  sconv_k<1, true, true><<<dim3(4, 28, 32), 256, 0, stream>>>(
      h1hi, h1lo, w2hi, w2lo, r2b, g2, b2, h2hi, h2lo, nullptr, 112, 112, 64, 1);
  sconv_k<2, true, true><<<dim3(2, 14, 64), 256, 0, stream>>>(
      h2hi, h2lo, w3hi, w3lo, r3b, g3, b3, h3hi, h3lo, nullptr, 56, 56, 128, 2);
  sconv_k<4, false, false><<<dim3(1, 7, 128), 256, 0, stream>>>(
      h3hi, h3lo, wphi, wplo, rpb, rpb, rpb, nullptr, nullptr, h4f32, 28, 28, 256, 4);

  rpn_head_k<<<(32 * NANCH + 255) / 256, 256, 0, stream>>>(h4f32, clsw, clsb, regw, regb, probs, boxes);
  nms_k<<<32, 256, 0, stream>>>(probs, boxes, dout, hasflag);

  // ---- Stage 2: CLM ----
  hipMemsetAsync(pooled, 0, 32 * 6272 * sizeof(float), stream);
  constexpr int CHUNK = 8;
  for (int c0 = 0; c0 < 32; c0 += CHUNK) {
    conv_k<4, 4, 8, true, 3><<<dim3(7, 7, CHUNK * 8), 256, 0, stream>>>(
        x + (size_t)c0 * 4 * 224 * 224, c1w, c1b, cg1, cb1, Wp, c1buf, nullptr, 224, 224, 64);
    c2band_k<<<dim3(7, 7, CHUNK * 8), 256, 0, stream>>>(
        c1buf, w2b, c2b, cg2, cb2, pooled, c0);
  }

  // ---- FC head ----
  fcsplit_k<<<dim3(8, 64), 64, 32 * 98 * 4, stream>>>(pooled, fc1w, fcpart, 6272, 512, 98);
  fcreduce_k<<<64, 256, 0, stream>>>(fcpart, fc1b, f1, 512, 64, 1);
  fcsplit_k<<<dim3(4, 16), 64, 32 * 32 * 4, stream>>>(f1, fc2w, fcpart, 512, 256, 32);
  fcreduce_k<<<32, 256, 0, stream>>>(fcpart, fc2b, f2, 256, 16, 1);
  fcsplit_k<<<dim3(2, 8), 64, 32 * 32 * 4, stream>>>(f2, fc3w, fcpart, 256, 128, 32);
  fcreduce_k<<<16, 256, 0, stream>>>(fcpart, fc3b, f3, 128, 8, 1);
  final_k<<<1, 64, 0, stream>>>(f3, fc4w, fc4b, hasflag, dout);
}

// Round 7
// 1161.892 us; speedup vs baseline: 7.7401x; 1.1529x over previous
//
#include <hip/hip_runtime.h>
#include <math.h>

constexpr int NANCH = 3136;           // 28*28*4
constexpr float SCORE_T = 0.7f;
constexpr float IOU_T = 0.3f;
constexpr int MAXP = 10;

typedef unsigned short u16;
typedef __attribute__((ext_vector_type(8))) short short8x;
typedef __attribute__((ext_vector_type(4))) float f32x4;

__device__ inline u16 f2bf(float f) {          // RNE float->bf16
  unsigned u = __builtin_bit_cast(unsigned, f);
  u += 0x7fffu + ((u >> 16) & 1u);
  return (u16)(u >> 16);
}
__device__ inline float bf2f(u16 h) {
  unsigned u = ((unsigned)h) << 16;
  return __builtin_bit_cast(float, u);
}

// =====================================================================
// Weight prep for 4-cin convs: [COUT][4][3][3] fp32 -> [cout][K=64] bf16
// hi/lo planes, K = tap*4 + cin, zero-padded 36..63.
// =====================================================================
__global__ __launch_bounds__(256) void w1prep_k(const float* __restrict__ w,
                                                u16* __restrict__ hi, u16* __restrict__ lo,
                                                int COUT) {
  const int i = blockIdx.x * 256 + threadIdx.x;
  if (i >= COUT * 64) return;
  const int k = i & 63, co = i >> 6;
  float v = 0.f;
  if (k < 36) { const int tap = k >> 2, cin = k & 3; v = w[co * 36 + cin * 9 + tap]; }
  const u16 h = f2bf(v);
  hi[i] = h;
  lo[i] = f2bf(v - bf2f(h));
}

// =====================================================================
// 4-cin 3x3 conv via im2col MFMA (K = 36 padded to 64).
// Block: 4 rows x 16 cols of one image; 4 waves.
// MODE 0 (CLM c1): plain bf16, COUT=64, BN+ReLU -> NHWC bf16 out.
// MODE 1 (RPN conv1): hi/lo x hi/lo (3 products), COUT=32,
//                     BN + affine-max-pool2x2 + ReLU -> NHWC hi/lo out.
// =====================================================================
template<int MODE>
__global__ __launch_bounds__(256) void c1mfma_k(
    const float* __restrict__ x,             // [*,4,224,224] fp32
    const u16* __restrict__ wfh, const u16* __restrict__ wfl,
    const float* __restrict__ bias, const float* __restrict__ gamma,
    const float* __restrict__ beta,
    u16* __restrict__ outhi, u16* __restrict__ outlo) {
  constexpr int COUT = MODE ? 32 : 64;
  constexpr int NF   = MODE ? 2 : 4;
  constexpr int PS   = MODE ? 136 : 72;      // patch row stride (shorts), 16B-aligned
  __shared__ u16 s_patch[64 * PS];
  __shared__ u16 s_wh[COUT * 72];
  __shared__ u16 s_wl[MODE ? COUT * 72 : 8];
  __shared__ float s_raw[4 * 6 * 18];
  __shared__ float s_pool[MODE ? 4 * 16 * 17 : 1];
  __shared__ u16 s_out[MODE ? 8 : 64 * 72];

  const int tid = threadIdx.x, lane = tid & 63, w = tid >> 6;
  const int lr = lane & 15, lg = lane >> 4;
  const int img = blockIdx.z;
  const int x0 = blockIdx.x * 16, y0 = blockIdx.y * 4;

  // zero K-pad regions of s_patch (36..63, and 100..127 for lo)
  for (int i = tid; i < 64 * 7; i += 256) {
    const int p = i / 7, q = i % 7;
    *(uint2*)&s_patch[p * PS + 36 + q * 4] = make_uint2(0, 0);
    if (MODE) *(uint2*)&s_patch[p * PS + 100 + q * 4] = make_uint2(0, 0);
  }
  // stage raw input 4cin x 6 x 18 (zero halo)
  for (int i = tid; i < 432; i += 256) {
    const int cin = i / 108, r = i % 108;
    const int ry = r / 18, rx = r % 18;
    const int gy = y0 - 1 + ry, gx = x0 - 1 + rx;
    float v = 0.f;
    if ((unsigned)gy < 224u && (unsigned)gx < 224u)
      v = x[(((size_t)img * 4 + cin) * 224 + gy) * 224 + gx];
    s_raw[i] = v;
  }
  // stage weights
  for (int i = tid; i < COUT * 8; i += 256) {
    const int co = i >> 3, q = i & 7;
    *(uint4*)&s_wh[co * 72 + q * 8] = *(const uint4*)&wfh[co * 64 + q * 8];
    if (MODE) *(uint4*)&s_wl[co * 72 + q * 8] = *(const uint4*)&wfl[co * 64 + q * 8];
  }
  __syncthreads();

  // build im2col patches
  for (int i = tid; i < 576; i += 256) {
    const int p = i / 9, tap = i % 9;
    const int ty = p >> 4, tx = p & 15;
    const int ky = tap / 3, kx = tap % 3;
    u16 h4[4], l4[4];
#pragma unroll
    for (int cin = 0; cin < 4; cin++) {
      const float v = s_raw[cin * 108 + (ty + ky) * 18 + (tx + kx)];
      h4[cin] = f2bf(v);
      if (MODE) l4[cin] = f2bf(v - bf2f(h4[cin]));
    }
    *(uint2*)&s_patch[p * PS + tap * 4] = *(uint2*)h4;
    if (MODE) *(uint2*)&s_patch[p * PS + 64 + tap * 4] = *(uint2*)l4;
  }
  __syncthreads();

  // MFMA: A pixel index for this lane
  int pA;
  if (MODE) pA = ((w >> 1) * 2 + (lr >> 3)) * 16 + (w & 1) * 8 + (lr & 7);
  else      pA = w * 16 + lr;

  f32x4 acc[NF];
#pragma unroll
  for (int nf = 0; nf < NF; nf++) acc[nf] = (f32x4)(0.f);

#pragma unroll
  for (int ks = 0; ks < 2; ks++) {
    const short8x ah = *(const short8x*)&s_patch[pA * PS + ks * 32 + lg * 8];
    short8x al;
    if (MODE) al = *(const short8x*)&s_patch[pA * PS + 64 + ks * 32 + lg * 8];
#pragma unroll
    for (int nf = 0; nf < NF; nf++) {
      const short8x bh = *(const short8x*)&s_wh[(nf * 16 + lr) * 72 + ks * 32 + lg * 8];
      if (MODE) {
        const short8x bl = *(const short8x*)&s_wl[(nf * 16 + lr) * 72 + ks * 32 + lg * 8];
        acc[nf] = __builtin_amdgcn_mfma_f32_16x16x32_bf16(al, bh, acc[nf], 0, 0, 0);
        acc[nf] = __builtin_amdgcn_mfma_f32_16x16x32_bf16(ah, bl, acc[nf], 0, 0, 0);
      }
      acc[nf] = __builtin_amdgcn_mfma_f32_16x16x32_bf16(ah, bh, acc[nf], 0, 0, 0);
    }
  }

  const float rsq = 1.f / sqrtf(1.f + 1e-5f);

  if (MODE == 0) {   // BN+ReLU -> s_out -> coalesced NHWC bf16
#pragma unroll
    for (int nf = 0; nf < 4; nf++) {
      const int co = nf * 16 + lr;
      const float bi = bias[co], scl = gamma[co] * rsq, shf = beta[co];
#pragma unroll
      for (int j = 0; j < 4; j++) {
        const float e = fmaxf((acc[nf][j] + bi) * scl + shf, 0.f);
        s_out[(w * 16 + lg * 4 + j) * 72 + co] = f2bf(e);
      }
    }
    __syncthreads();
    for (int i = tid; i < 512; i += 256) {
      const int p = i >> 3, q = i & 7;
      const int oy = y0 + (p >> 4), ox = x0 + (p & 15);
      *(uint4*)&outhi[(((size_t)img * 224 + oy) * 224 + ox) * 64 + q * 8] =
          *(uint4*)&s_out[p * 72 + q * 8];
    }
  } else {           // affine -> 2x2 maxpool -> ReLU -> NHWC hi/lo
#pragma unroll
    for (int nf = 0; nf < 2; nf++) {
      const int co = nf * 16 + lr;
      const float bi = bias[co], scl = gamma[co] * rsq, shf = beta[co];
#pragma unroll
      for (int j = 0; j < 4; j++) {
        const int m = lg * 4 + j;
        s_pool[w * 272 + m * 17 + lr] = (acc[nf][j] + bi) * scl + shf;
      }
      __syncthreads();
      {
        const int pc = lane >> 4, n = lane & 15;
        const float* sp = &s_pool[w * 272];
        float m0 = fmaxf(sp[(pc * 2) * 17 + n], sp[(pc * 2 + 1) * 17 + n]);
        float m1 = fmaxf(sp[(pc * 2 + 8) * 17 + n], sp[(pc * 2 + 9) * 17 + n]);
        const float mm = fmaxf(fmaxf(m0, m1), 0.f);
        const int py = (y0 >> 1) + (w >> 1), px = (x0 >> 1) + (w & 1) * 4 + pc;
        const size_t o = (((size_t)img * 112 + py) * 112 + px) * 32 + nf * 16 + n;
        const u16 h = f2bf(mm);
        outhi[o] = h; outlo[o] = f2bf(mm - bf2f(h));
      }
      __syncthreads();
    }
  }
}

// =====================================================================
// Weight prep: [COUT][CIN][3][3] fp32 -> [tap][cout][cin] bf16 hi/lo planes
// =====================================================================
__global__ __launch_bounds__(256) void wsplit_k(const float* __restrict__ w,
                                                u16* __restrict__ hi, u16* __restrict__ lo,
                                                int COUT, int CIN) {
  const int n = 9 * COUT * CIN;
  const int i = blockIdx.x * 256 + threadIdx.x;
  if (i >= n) return;
  const int cin = i % CIN; int r = i / CIN;
  const int cout = r % COUT; const int tap = r / COUT;
  const float v = w[((size_t)cout * CIN + cin) * 9 + tap];
  const u16 h = f2bf(v);
  hi[i] = h; lo[i] = f2bf(v - bf2f(h));
}

// single-plane bf16 prep for CLM c2: [128,64,3,3] -> [tap][128][64]
__global__ __launch_bounds__(256) void w2b_k(const float* __restrict__ w,
                                             u16* __restrict__ wb) {
  const int i = blockIdx.x * 256 + threadIdx.x;   // 73728
  if (i >= 73728) return;
  const int cin = i & 63; const int r = i >> 6;
  const int cout = r & 127; const int tap = r >> 7;
  wb[i] = f2bf(w[(((size_t)cout * 64 + cin) * 3 + tap / 3) * 3 + tap % 3]);
}

// =====================================================================
// Split-bf16 MFMA 3x3 conv (fp32-accurate via hi/lo x hi/lo, 3 products).
// Input NHWC hi/lo planes. Block: 4-row x 32-col band, 64 couts.
// POOL: fused BN+ReLU+2x2 maxpool, NHWC hi/lo out.
// !POOL: +bias+ReLU, NHWC fp32 out (rpn final conv).
// =====================================================================
template<int CINCH, bool POOL, bool BN>
__global__ __launch_bounds__(256) void sconv_k(
    const u16* __restrict__ ahi, const u16* __restrict__ alo,
    const u16* __restrict__ whi, const u16* __restrict__ wlo,
    const float* __restrict__ bias, const float* __restrict__ gamma,
    const float* __restrict__ beta,
    u16* __restrict__ ohi, u16* __restrict__ olo, float* __restrict__ of32,
    int H, int W, int COUT, int cog) {
  __shared__ u16 s_in[6 * 34 * 72];   // [row][col][hi32|lo32], col stride 72
  __shared__ u16 s_w[64 * 72];        // [cout][hi32|lo32]
  const int tid = threadIdx.x, lane = tid & 63, wave = tid >> 6;
  const int wm = wave >> 1, wn = wave & 1, lr = lane & 15, lg = lane >> 4;
  const int img = blockIdx.z / cog, co0 = (blockIdx.z % cog) * 64;
  const int x0 = blockIdx.x * 32, band = blockIdx.y;
  const int CIN = CINCH * 32;

  f32x4 acc[4][2];
#pragma unroll
  for (int mi = 0; mi < 4; ++mi) { acc[mi][0] = (f32x4)(0.f); acc[mi][1] = (f32x4)(0.f); }

  for (int cc2 = 0; cc2 < CINCH; ++cc2) {
    // stage 6 rows x 34 cols x (32hi + 32lo) cin
    for (int idx = tid; idx < 1632; idx += 256) {
      const int r = idx / 272, rem = idx % 272;
      const int c = rem >> 3, q = rem & 7, pl = q >> 2, qq = q & 3;
      const int gy = band * 4 - 1 + r, gx = x0 - 1 + c;
      uint4 v = make_uint4(0, 0, 0, 0);
      if ((unsigned)gy < (unsigned)H && (unsigned)gx < (unsigned)W) {
        const u16* src = pl ? alo : ahi;
        v = *(const uint4*)(src + ((size_t)(img * H + gy) * W + gx) * CIN + cc2 * 32 + qq * 8);
      }
      *(uint4*)(&s_in[(r * 34 + c) * 72 + pl * 32 + qq * 8]) = v;
    }
    for (int tap = 0; tap < 9; ++tap) {
      const int ky = tap / 3, kx = tap % 3;
      for (int idx = tid; idx < 512; idx += 256) {
        const int cout = idx >> 3, q = idx & 7, pl = q >> 2, qq = q & 3;
        const u16* src = pl ? wlo : whi;
        uint4 v = *(const uint4*)(src + ((size_t)tap * COUT + co0 + cout) * CIN + cc2 * 32 + qq * 8);
        *(uint4*)(&s_w[cout * 72 + pl * 32 + qq * 8]) = v;
      }
      __syncthreads();
      short8x ah[4], al[4], bh[2], bl[2];
#pragma unroll
      for (int mi = 0; mi < 4; ++mi) {
        const int base = ((2 * wm + (mi >> 1) + ky) * 34 + (mi & 1) * 16 + lr + kx) * 72;
        ah[mi] = *(const short8x*)(&s_in[base + lg * 8]);
        al[mi] = *(const short8x*)(&s_in[base + 32 + lg * 8]);
      }
#pragma unroll
      for (int ni = 0; ni < 2; ++ni) {
        const int wb2 = (wn * 32 + ni * 16 + lr) * 72;
        bh[ni] = *(const short8x*)(&s_w[wb2 + lg * 8]);
        bl[ni] = *(const short8x*)(&s_w[wb2 + 32 + lg * 8]);
      }
#pragma unroll
      for (int mi = 0; mi < 4; ++mi)
#pragma unroll
        for (int ni = 0; ni < 2; ++ni) {
          acc[mi][ni] = __builtin_amdgcn_mfma_f32_16x16x32_bf16(al[mi], bh[ni], acc[mi][ni], 0, 0, 0);
          acc[mi][ni] = __builtin_amdgcn_mfma_f32_16x16x32_bf16(ah[mi], bl[ni], acc[mi][ni], 0, 0, 0);
          acc[mi][ni] = __builtin_amdgcn_mfma_f32_16x16x32_bf16(ah[mi], bh[ni], acc[mi][ni], 0, 0, 0);
        }
      __syncthreads();
    }
  }

  const float rsq = 1.f / sqrtf(1.f + 1e-5f);
#pragma unroll
  for (int ni = 0; ni < 2; ++ni) {
    const int cout = co0 + wn * 32 + ni * 16 + lr;
    const float bi = bias[cout];
    const float scl = BN ? gamma[cout] * rsq : 1.f;
    const float shf = BN ? beta[cout] : 0.f;
    if (POOL) {
      const int OH = H >> 1, OW = W >> 1;
      const int py = band * 2 + wm;
#pragma unroll
      for (int ch = 0; ch < 2; ++ch)
#pragma unroll
        for (int jp = 0; jp < 2; ++jp) {
          float m = (acc[ch][ni][2 * jp] + bi) * scl + shf;
          m = fmaxf(m, (acc[ch][ni][2 * jp + 1] + bi) * scl + shf);
          m = fmaxf(m, (acc[ch + 2][ni][2 * jp] + bi) * scl + shf);
          m = fmaxf(m, (acc[ch + 2][ni][2 * jp + 1] + bi) * scl + shf);
          m = fmaxf(m, 0.f);
          const int px = (x0 >> 1) + ch * 8 + lg * 2 + jp;
          if (px < OW) {
            const size_t o = ((size_t)(img * OH + py) * OW + px) * COUT + cout;
            const u16 h = f2bf(m);
            ohi[o] = h; olo[o] = f2bf(m - bf2f(h));
          }
        }
    } else {
#pragma unroll
      for (int mi = 0; mi < 4; ++mi) {
        const int row = band * 4 + 2 * wm + (mi >> 1);
#pragma unroll
        for (int j = 0; j < 4; ++j) {
          const int px = x0 + (mi & 1) * 16 + lg * 4 + j;
          if (px < W)
            of32[((size_t)(img * H + row) * W + px) * COUT + cout] =
                fmaxf(acc[mi][ni][j] + bi, 0.f);
        }
      }
    }
  }
}

// =====================================================================
// CLM conv2 MFMA, band-per-block: one 4-row band of a 32x32 pool tile,
// all 128 couts. Pool partial -> global atomicAdd (pooled pre-zeroed).
// =====================================================================
__global__ __launch_bounds__(256) void c2band_k(
    const u16* __restrict__ act, const u16* __restrict__ wb,
    const float* __restrict__ bias, const float* __restrict__ gamma,
    const float* __restrict__ beta, float* __restrict__ pooled, int gimg0) {
  __shared__ u16 s_in[6 * 34 * 72];
  __shared__ u16 s_w[2 * 128 * 40];
  __shared__ float s_pool[128];

  const int tid = threadIdx.x;
  const int lane = tid & 63, wave = tid >> 6;
  const int wm = wave >> 1, wn = wave & 1;
  const int lr = lane & 15, lg = lane >> 4;
  const int img = blockIdx.z >> 3, band = blockIdx.z & 7;
  const int x0 = blockIdx.x * 32, y0 = blockIdx.y * 32;
  const float rsq = 1.f / sqrtf(1.f + 1e-5f);

  if (tid < 128) s_pool[tid] = 0.f;

  for (int idx = tid; idx < 1632; idx += 256) {
    const int r = idx / 272, rem = idx % 272;
    const int c = rem >> 3, q = rem & 7;
    const int gy = y0 + band * 4 - 1 + r, gx = x0 - 1 + c;
    uint4 v = make_uint4(0, 0, 0, 0);
    if ((unsigned)gy < 224u && (unsigned)gx < 224u)
      v = *(const uint4*)(act + (((size_t)img * 224 + gy) * 224 + gx) * 64 + q * 8);
    *(uint4*)(&s_in[(r * 34 + c) * 72 + q * 8]) = v;
  }

  f32x4 acc[4][4];
#pragma unroll
  for (int mi = 0; mi < 4; ++mi)
#pragma unroll
    for (int ni = 0; ni < 4; ++ni) acc[mi][ni] = (f32x4)(0.f);

  for (int tap = 0; tap < 9; ++tap) {
    const int ky = tap / 3, kx = tap % 3;
    for (int idx = tid; idx < 1024; idx += 256) {
      const int cout = idx >> 3, q = idx & 7;
      uint4 v = *(const uint4*)(wb + ((size_t)tap * 128 + cout) * 64 + q * 8);
      *(uint4*)(&s_w[(q >> 2) * 5120 + cout * 40 + (q & 3) * 8]) = v;
    }
    __syncthreads();
#pragma unroll
    for (int h = 0; h < 2; ++h) {
      short8x a[4], bf[4];
#pragma unroll
      for (int mi = 0; mi < 4; ++mi) {
        const int rl = wm * 2 + (mi >> 1) + ky;
        const int cc = (mi & 1) * 16 + lr + kx;
        a[mi] = *(const short8x*)(&s_in[(rl * 34 + cc) * 72 + h * 32 + lg * 8]);
      }
#pragma unroll
      for (int ni = 0; ni < 4; ++ni) {
        const int co = wn * 64 + ni * 16 + lr;
        bf[ni] = *(const short8x*)(&s_w[h * 5120 + co * 40 + lg * 8]);
      }
#pragma unroll
      for (int mi = 0; mi < 4; ++mi)
#pragma unroll
        for (int ni = 0; ni < 4; ++ni)
          acc[mi][ni] = __builtin_amdgcn_mfma_f32_16x16x32_bf16(a[mi], bf[ni], acc[mi][ni], 0, 0, 0);
    }
    __syncthreads();
  }
#pragma unroll
  for (int ni = 0; ni < 4; ++ni) {
    const int co = wn * 64 + ni * 16 + lr;
    const float bi = bias[co], scl = gamma[co] * rsq, shf = beta[co];
    float s = 0.f;
#pragma unroll
    for (int mi = 0; mi < 4; ++mi)
#pragma unroll
      for (int j = 0; j < 4; ++j)
        s += fmaxf((acc[mi][ni][j] + bi) * scl + shf, 0.f);
    atomicAdd(&s_pool[co], s);
  }
  __syncthreads();
  if (tid < 128)
    atomicAdd(&pooled[(size_t)(gimg0 + img) * 6272 + tid * 49 + blockIdx.y * 7 + blockIdx.x],
              s_pool[tid] * (1.f / 1024.f));
}

// =====================================================================
// RPN head: feat NHWC [B,784,256]. 1x1 cls/reg + softmax + decode.
// =====================================================================
__global__ __launch_bounds__(256) void rpn_head_k(
    const float* __restrict__ feat,
    const float* __restrict__ clsw, const float* __restrict__ clsb,
    const float* __restrict__ regw, const float* __restrict__ regb,
    float* __restrict__ probs, float* __restrict__ boxes) {
  const int gid = blockIdx.x * 256 + threadIdx.x;
  if (gid >= 32 * NANCH) return;
  const int a = gid & 3;
  int r = gid >> 2;
  const int x = r % 28; r /= 28;
  const int y = r % 28;
  const int b = r / 28;

  const float* f = feat + ((size_t)b * 784 + y * 28 + x) * 256;
  float c0 = clsb[2 * a], c1 = clsb[2 * a + 1];
  float r0 = regb[4 * a], r1 = regb[4 * a + 1], r2 = regb[4 * a + 2], r3 = regb[4 * a + 3];
#pragma unroll 4
  for (int c = 0; c < 256; c++) {
    const float fv = f[c];
    c0 = fmaf(fv, clsw[(2 * a) * 256 + c], c0);
    c1 = fmaf(fv, clsw[(2 * a + 1) * 256 + c], c1);
    r0 = fmaf(fv, regw[(4 * a) * 256 + c], r0);
    r1 = fmaf(fv, regw[(4 * a + 1) * 256 + c], r1);
    r2 = fmaf(fv, regw[(4 * a + 2) * 256 + c], r2);
    r3 = fmaf(fv, regw[(4 * a + 3) * 256 + c], r3);
  }
  const float p = 1.f / (1.f + expf(c0 - c1));

  const float cx = (x + 0.5f) * (1.f / 28.f);
  const float cy = (y + 0.5f) * (1.f / 28.f);
  const float sz = (float)(16 << a) * (1.f / 224.f);
  const float ncx = cx + r0 * 0.1f, ncy = cy + r1 * 0.1f;
  const float nw = sz * expf(r2 * 0.2f), nh = sz * expf(r3 * 0.2f);
  const float x1 = fminf(fmaxf(ncx - nw * 0.5f, 0.f), 1.f);
  const float y1 = fminf(fmaxf(ncy - nh * 0.5f, 0.f), 1.f);
  const float x2 = fminf(fmaxf(ncx + nw * 0.5f, 0.f), 1.f);
  const float y2 = fminf(fmaxf(ncy + nh * 0.5f, 0.f), 1.f);

  probs[gid] = p;
  ((float4*)boxes)[gid] = make_float4(x1, y1, x2, y2);
}

// =====================================================================
// Greedy NMS, one block per image (matches jax.lax.scan semantics).
// =====================================================================
__global__ __launch_bounds__(256) void nms_k(
    const float* __restrict__ probs, const float* __restrict__ boxes,
    float* __restrict__ dout, int* __restrict__ hasflag) {
  const int b = blockIdx.x;
  const int t = threadIdx.x;
  __shared__ float sc[NANCH];
  __shared__ float ar[NANCH];
  __shared__ float4 bx[NANCH];
  __shared__ float rv[256];
  __shared__ int   ri[256];
  __shared__ int s_any, s_sel[MAXP], s_ok[MAXP];

  if (t == 0) s_any = 0;
  __syncthreads();

  int anyl = 0;
  for (int i = t; i < NANCH; i += 256) {
    const float p = probs[(size_t)b * NANCH + i];
    const float4 bb = ((const float4*)boxes)[(size_t)b * NANCH + i];
    bx[i] = bb;
    ar[i] = (bb.z - bb.x) * (bb.w - bb.y);
    sc[i] = (p > SCORE_T) ? p : -INFINITY;
    if (p > SCORE_T) anyl = 1;
  }
  if (anyl) atomicOr(&s_any, 1);
  __syncthreads();

  for (int it = 0; it < MAXP; ++it) {
    float bv = -INFINITY; int bi = 0x7fffffff;
    for (int i = t; i < NANCH; i += 256) {
      const float v = sc[i];
      if (v > bv || (v == bv && i < bi)) { bv = v; bi = i; }
    }
    rv[t] = bv; ri[t] = bi;
    __syncthreads();
    for (int st = 128; st > 0; st >>= 1) {
      if (t < st) {
        const float ov = rv[t + st]; const int oi = ri[t + st];
        if (ov > rv[t] || (ov == rv[t] && oi < ri[t])) { rv[t] = ov; ri[t] = oi; }
      }
      __syncthreads();
    }
    if (t == 0) { s_sel[it] = ri[0]; s_ok[it] = (rv[0] > -INFINITY) ? 1 : 0; }
    __syncthreads();
    const int sel = s_sel[it];
    const int ok  = s_ok[it];
    if (ok) {
      const float4 bs = bx[sel]; const float as = ar[sel];
      for (int i = t; i < NANCH; i += 256) {
        const float xx1 = fmaxf(bs.x, bx[i].x), yy1 = fmaxf(bs.y, bx[i].y);
        const float xx2 = fminf(bs.z, bx[i].z), yy2 = fminf(bs.w, bx[i].w);
        const float inter = fmaxf(xx2 - xx1, 0.f) * fmaxf(yy2 - yy1, 0.f);
        const float iou = inter / (as + ar[i] - inter);
        if (iou > IOU_T || i == sel) sc[i] = -INFINITY;
      }
    }
    __syncthreads();
  }

  if (t < MAXP) {
    const int sel = s_ok[t] ? s_sel[t] : 0;
    const float okf = s_ok[t] ? 1.f : 0.f;
    const float4 bb = bx[sel];
    float* kb = dout + 64;
    float* ks = dout + 64 + 32 * MAXP * 4;
    float* ko = dout + 64 + 32 * MAXP * 5;
    const size_t base = ((size_t)b * MAXP + t) * 4;
    kb[base + 0] = bb.x * okf; kb[base + 1] = bb.y * okf;
    kb[base + 2] = bb.z * okf; kb[base + 3] = bb.w * okf;
    ks[b * MAXP + t] = probs[(size_t)b * NANCH + sel] * okf;
    ko[b * MAXP + t] = okf;
  }
  if (t == 0) hasflag[b] = s_any;
}

// =====================================================================
// FC split-K: weights read exactly once across the grid.
// =====================================================================
__global__ __launch_bounds__(64) void fcsplit_k(
    const float* __restrict__ x, const float* __restrict__ w,
    float* __restrict__ part, int K, int N, int kchunk) {
  extern __shared__ float sx[];
  const int o = blockIdx.x * 64 + threadIdx.x;
  const int k0 = blockIdx.y * kchunk;
  for (int i = threadIdx.x; i < 32 * kchunk; i += 64) {
    const int bb = i / kchunk, kk = i % kchunk;
    sx[i] = x[(size_t)bb * K + k0 + kk];
  }
  __syncthreads();
  float acc[32];
#pragma unroll
  for (int bb = 0; bb < 32; bb++) acc[bb] = 0.f;
#pragma unroll 8
  for (int kk = 0; kk < kchunk; kk++) {
    const float wv = w[(size_t)(k0 + kk) * N + o];
#pragma unroll
    for (int bb = 0; bb < 32; bb++) acc[bb] = fmaf(sx[bb * kchunk + kk], wv, acc[bb]);
  }
  float* p = part + (size_t)blockIdx.y * 32 * N + o;
#pragma unroll
  for (int bb = 0; bb < 32; bb++) p[(size_t)bb * N] = acc[bb];
}

__global__ __launch_bounds__(256) void fcreduce_k(
    const float* __restrict__ part, const float* __restrict__ bias,
    float* __restrict__ y, int N, int KT, int dorelu) {
  const int i = blockIdx.x * 256 + threadIdx.x;
  if (i >= 32 * N) return;
  const int o = i % N;
  float s = bias[o];
  for (int kt = 0; kt < KT; kt++) s += part[(size_t)kt * 32 * N + i];
  y[i] = dorelu ? fmaxf(s, 0.f) : s;
}

__global__ __launch_bounds__(64) void final_k(
    const float* __restrict__ f3, const float* __restrict__ w,
    const float* __restrict__ bi, const int* __restrict__ hasflag,
    float* __restrict__ dout) {
  const int t = threadIdx.x;
  if (t >= 64) return;
  const int b = t >> 1, j = t & 1;
  float acc = bi[j];
#pragma unroll 4
  for (int k = 0; k < 128; k++) acc = fmaf(f3[b * 128 + k], w[k * 2 + j], acc);
  dout[b * 2 + j] = hasflag[b] ? acc : (j == 0 ? 1.f : 0.f);
}

// =====================================================================
extern "C" void kernel_launch(void* const* d_in, const int* in_sizes, int n_in,
                              void* d_out, int out_size, void* d_ws, size_t ws_size,
                              hipStream_t stream) {
  const float* x    = (const float*)d_in[0];
  const float* r1w  = (const float*)d_in[1];  const float* r1b = (const float*)d_in[2];
  const float* g1   = (const float*)d_in[3];  const float* b1  = (const float*)d_in[4];
  const float* r2w  = (const float*)d_in[5];  const float* r2b = (const float*)d_in[6];
  const float* g2   = (const float*)d_in[7];  const float* b2  = (const float*)d_in[8];
  const float* r3w  = (const float*)d_in[9];  const float* r3b = (const float*)d_in[10];
  const float* g3   = (const float*)d_in[11]; const float* b3  = (const float*)d_in[12];
  const float* rpw  = (const float*)d_in[13]; const float* rpb = (const float*)d_in[14];
  const float* clsw = (const float*)d_in[15]; const float* clsb = (const float*)d_in[16];
  const float* regw = (const float*)d_in[17]; const float* regb = (const float*)d_in[18];
  const float* c1w  = (const float*)d_in[19]; const float* c1b = (const float*)d_in[20];
  const float* cg1  = (const float*)d_in[21]; const float* cb1 = (const float*)d_in[22];
  const float* c2w  = (const float*)d_in[23]; const float* c2b = (const float*)d_in[24];
  const float* cg2  = (const float*)d_in[25]; const float* cb2 = (const float*)d_in[26];
  const float* fc1w = (const float*)d_in[27]; const float* fc1b = (const float*)d_in[28];
  const float* fc2w = (const float*)d_in[29]; const float* fc2b = (const float*)d_in[30];
  const float* fc3w = (const float*)d_in[31]; const float* fc3b = (const float*)d_in[32];
  const float* fc4w = (const float*)d_in[33]; const float* fc4b = (const float*)d_in[34];
  float* dout = (float*)d_out;
  float* Wp = (float*)d_ws;

  // ---- workspace layout (float slots) ----
  const size_t o_h1   = 0;                      // hi/lo NHWC 32x112x112x32: 2x12.85M shorts
  const size_t o_h2   = 12845056;               // hi/lo NHWC 32x56x56x64
  const size_t o_h3   = o_h2 + 6422528;         // hi/lo NHWC 32x28x28x128
  const size_t o_prob = o_h3 + 3211264;
  const size_t o_box  = o_prob + 100352;
  const size_t o_flag = o_box + 401408;
  const size_t o_pool = o_flag + 32;
  const size_t o_f1   = o_pool + 200704;
  const size_t o_f2   = o_f1 + 16384;
  const size_t o_f3   = o_f2 + 8192;
  const size_t o_w2b  = o_f3 + 4096;            // 73728 shorts (CLM c2 bf16)
  const size_t o_w2s  = o_w2b + 36864;          // conv2 hi+lo: 2x18432 shorts
  const size_t o_w3s  = o_w2s + 18432;          // conv3 hi+lo: 2x73728 shorts
  const size_t o_wps  = o_w3s + 73728;          // rpw  hi+lo: 2x294912 shorts
  const size_t o_w1r  = o_wps + 294912;         // rpn conv1 [32][64] hi+lo: 2x2048 shorts
  const size_t o_w1c  = o_w1r + 2048;           // clm c1 [64][64] hi+lo: 2x4096 shorts

  u16* h1hi = (u16*)(Wp + o_h1); u16* h1lo = h1hi + 12845056;
  u16* h2hi = (u16*)(Wp + o_h2); u16* h2lo = h2hi + 6422528;
  u16* h3hi = (u16*)(Wp + o_h3); u16* h3lo = h3hi + 3211264;
  float* probs = Wp + o_prob; float* boxes = Wp + o_box;
  int* hasflag = (int*)(Wp + o_flag);
  float* pooled = Wp + o_pool;
  float* f1 = Wp + o_f1; float* f2 = Wp + o_f2; float* f3 = Wp + o_f3;
  u16* w2b  = (u16*)(Wp + o_w2b);
  u16* w2hi = (u16*)(Wp + o_w2s); u16* w2lo = w2hi + 18432;
  u16* w3hi = (u16*)(Wp + o_w3s); u16* w3lo = w3hi + 73728;
  u16* wphi = (u16*)(Wp + o_wps); u16* wplo = wphi + 294912;
  u16* w1rhi = (u16*)(Wp + o_w1r); u16* w1rlo = w1rhi + 2048;
  u16* w1chi = (u16*)(Wp + o_w1c); u16* w1clo = w1chi + 4096;
  // aliases over dead h1 region (safe by stream order):
  float* h4f32 = Wp + o_h1;            // rpn feat NHWC fp32 [32,784,256] = 6.42M
  u16*   c1buf = (u16*)(Wp + o_h1);    // CLM c1 NHWC bf16, 8 imgs = 25.69M shorts
  float* fcpart = Wp + o_h1;           // fc split partials (<= 1.05M)

  // ---- weight prep ----
  wsplit_k<<<(9 * 64 * 32 + 255) / 256, 256, 0, stream>>>(r2w, w2hi, w2lo, 64, 32);
  wsplit_k<<<(9 * 128 * 64 + 255) / 256, 256, 0, stream>>>(r3w, w3hi, w3lo, 128, 64);
  wsplit_k<<<(9 * 256 * 128 + 255) / 256, 256, 0, stream>>>(rpw, wphi, wplo, 256, 128);
  w2b_k<<<288, 256, 0, stream>>>(c2w, w2b);
  w1prep_k<<<8, 256, 0, stream>>>(r1w, w1rhi, w1rlo, 32);
  w1prep_k<<<16, 256, 0, stream>>>(c1w, w1chi, w1clo, 64);

  // ---- Stage 1: RPN backbone ----
  c1mfma_k<1><<<dim3(14, 56, 32), 256, 0, stream>>>(
      x, w1rhi, w1rlo, r1b, g1, b1, h1hi, h1lo);
  sconv_k<1, true, true><<<dim3(4, 28, 32), 256, 0, stream>>>(
      h1hi, h1lo, w2hi, w2lo, r2b, g2, b2, h2hi, h2lo, nullptr, 112, 112, 64, 1);
  sconv_k<2, true, true><<<dim3(2, 14, 64), 256, 0, stream>>>(
      h2hi, h2lo, w3hi, w3lo, r3b, g3, b3, h3hi, h3lo, nullptr, 56, 56, 128, 2);
  sconv_k<4, false, false><<<dim3(1, 7, 128), 256, 0, stream>>>(
      h3hi, h3lo, wphi, wplo, rpb, rpb, rpb, nullptr, nullptr, h4f32, 28, 28, 256, 4);

  rpn_head_k<<<(32 * NANCH + 255) / 256, 256, 0, stream>>>(h4f32, clsw, clsb, regw, regb, probs, boxes);
  nms_k<<<32, 256, 0, stream>>>(probs, boxes, dout, hasflag);

  // ---- Stage 2: CLM ----
  hipMemsetAsync(pooled, 0, 32 * 6272 * sizeof(float), stream);
  constexpr int CHUNK = 8;
  for (int c0 = 0; c0 < 32; c0 += CHUNK) {
    c1mfma_k<0><<<dim3(14, 56, CHUNK), 256, 0, stream>>>(
        x + (size_t)c0 * 4 * 224 * 224, w1chi, w1clo, c1b, cg1, cb1, c1buf, nullptr);
    c2band_k<<<dim3(7, 7, CHUNK * 8), 256, 0, stream>>>(
        c1buf, w2b, c2b, cg2, cb2, pooled, c0);
  }

  // ---- FC head ----
  fcsplit_k<<<dim3(8, 64), 64, 32 * 98 * 4, stream>>>(pooled, fc1w, fcpart, 6272, 512, 98);
  fcreduce_k<<<64, 256, 0, stream>>>(fcpart, fc1b, f1, 512, 64, 1);
  fcsplit_k<<<dim3(4, 16), 64, 32 * 32 * 4, stream>>>(f1, fc2w, fcpart, 512, 256, 32);
  fcreduce_k<<<32, 256, 0, stream>>>(fcpart, fc2b, f2, 256, 16, 1);
  fcsplit_k<<<dim3(2, 8), 64, 32 * 32 * 4, stream>>>(f2, fc3w, fcpart, 256, 128, 32);
  fcreduce_k<<<16, 256, 0, stream>>>(fcpart, fc3b, f3, 128, 8, 1);
  final_k<<<1, 64, 0, stream>>>(f3, fc4w, fc4b, hasflag, dout);
}